// Round 1
// baseline (8713.055 us; speedup 1.0000x reference)
//
#include <hip/hip_runtime.h>
#include <hip/hip_bf16.h>
#include <stdint.h>

// ---------- helpers ----------
#define AS1(p) ((const __attribute__((address_space(1))) void*)(p))
#define AS3(p) ((__attribute__((address_space(3))) void*)(p))

typedef __bf16 bf16x8 __attribute__((ext_vector_type(8)));
typedef float f32x4 __attribute__((ext_vector_type(4)));

__device__ __forceinline__ unsigned short f2bf(float f) {
  unsigned u = __builtin_bit_cast(unsigned, f);
  u = (u + 0x7FFFu + ((u >> 16) & 1u)) >> 16;   // RNE
  return (unsigned short)u;
}

// ---------- constants ----------
// B=16 L=4096 N=64 D=64 H=4 WAVE=16 T=256 DFF=256 DH=16 TOPK=16

// ---------- k_bias: cosine-sim top-16 -> additive bias [64][64] ----------
__global__ void k_bias(const float* __restrict__ emb, float* __restrict__ bias) {
  __shared__ float e[64 * 64];
  __shared__ float nrm[64];
  __shared__ float cosr[64 * 65];
  int tid = threadIdx.x;  // 64 threads
  for (int idx = tid; idx < 4096; idx += 64) e[idx] = emb[idx];
  __syncthreads();
  float s = 0.f;
  for (int j = 0; j < 64; j++) { float v = e[tid * 64 + j]; s += v * v; }
  nrm[tid] = sqrtf(s);
  __syncthreads();
  for (int jj = 0; jj < 64; jj++) {
    float d = 0.f;
    for (int kk = 0; kk < 64; kk++) d += e[tid * 64 + kk] * e[jj * 64 + kk];
    cosr[tid * 65 + jj] = d / (nrm[tid] * nrm[jj]);
  }
  // greedy top-16 (strict > keeps smallest index on ties, matching lax.top_k)
  unsigned long long sel = 0ull;
  for (int it = 0; it < 16; it++) {
    float best = -1e30f; int bi = 0;
    for (int j = 0; j < 64; j++) {
      if ((sel >> j) & 1ull) continue;
      float c = cosr[tid * 65 + j];
      if (c > best) { best = c; bi = j; }
    }
    sel |= (1ull << bi);
  }
  for (int j = 0; j < 64; j++)
    bias[tid * 64 + j] = ((sel >> j) & 1ull) ? 0.0f : -1e9f;
}

// ---------- k_conv: h[b,t,n,d] = sum_w x[b,t*16+w,d]*conv_w[d,n,w] + conv_b[d,n] ----------
__global__ void k_conv(const float* __restrict__ x, const float* __restrict__ conv_w,
                       const float* __restrict__ conv_b, float* __restrict__ h) {
  int bt = blockIdx.x;           // b*256 + t
  int b = bt >> 8, t = bt & 255;
  __shared__ float xs[16 * 64];
  int tid = threadIdx.x;
  for (int idx = tid; idx < 1024; idx += 256)
    xs[idx] = x[((size_t)b * 4096 + t * 16 + (idx >> 6)) * 64 + (idx & 63)];
  __syncthreads();
  int d = tid & 63, n0 = (tid >> 6) << 4;
  float xv[16];
  #pragma unroll
  for (int w = 0; w < 16; w++) xv[w] = xs[w * 64 + d];
  for (int n = n0; n < n0 + 16; n++) {
    float acc = conv_b[d * 64 + n];
    const float* wp = &conv_w[(d * 64 + n) * 16];
    #pragma unroll
    for (int w = 0; w < 16; w++) acc += xv[w] * wp[w];
    h[((size_t)bt * 64 + n) * 64 + d] = acc;
  }
}

// ---------- k_layer: one fused transformer layer for one (b,t) per block ----------
__global__ __launch_bounds__(256, 1) void k_layer(
    float* __restrict__ hbuf, const float* __restrict__ emb, const float* __restrict__ bias,
    const float* __restrict__ Wq, const float* __restrict__ bq,
    const float* __restrict__ Wk, const float* __restrict__ bk,
    const float* __restrict__ Wv, const float* __restrict__ bv,
    const float* __restrict__ Wo, const float* __restrict__ bo,
    const float* __restrict__ ln1g, const float* __restrict__ ln1b,
    const float* __restrict__ ln2g, const float* __restrict__ ln2b,
    const float* __restrict__ W1, const float* __restrict__ b1,
    const float* __restrict__ W2, const float* __restrict__ b2,
    const float* __restrict__ res1, const float* __restrict__ res2, int l) {
  __shared__ float smem[25088];   // 100,352 B
  float* hs  = smem;                // [64][65] h (residual / post-LN h)
  float* xs  = smem + 4160;         // [64][65] hin / x pre-LN
  float* qs  = smem + 8320;
  float* ks_ = smem + 12480;
  float* vs  = smem + 16640;
  float* os_ = smem + 20800;
  float* gs  = qs;                  // [64][257] overlays qs..os after attention
  float* mv  = smem + 24960;        // [64][2]
  int bt = blockIdx.x, tid = threadIdx.x;
  size_t base = (size_t)bt * 4096;
  const float* wq = Wq + l * 4096; const float* wk = Wk + l * 4096;
  const float* wv = Wv + l * 4096; const float* wo = Wo + l * 4096;
  const float* w1 = W1 + l * 16384; const float* w2 = W2 + l * 16384;
  float r1 = res1[l], r2 = res2[l];

  // 1. load h; hin = h + emb
  for (int idx = tid; idx < 4096; idx += 256) {
    float hv = hbuf[base + idx];
    int n = idx >> 6, d = idx & 63;
    hs[n * 65 + d] = hv;
    xs[n * 65 + d] = hv + emb[idx];
  }
  __syncthreads();

  // 2. q,k,v = hin @ W + b   (thread: n = tid>>2, 16 cols starting (tid&3)*16)
  {
    int n = tid >> 2, d0 = (tid & 3) << 4;
    float aq[16], ak[16], av[16];
    #pragma unroll
    for (int j = 0; j < 16; j++) { aq[j] = bq[l * 64 + d0 + j]; ak[j] = bk[l * 64 + d0 + j]; av[j] = bv[l * 64 + d0 + j]; }
    for (int kk = 0; kk < 64; kk++) {
      float a = xs[n * 65 + kk];
      const float* pq = &wq[kk * 64 + d0];
      const float* pk = &wk[kk * 64 + d0];
      const float* pv = &wv[kk * 64 + d0];
      #pragma unroll
      for (int j = 0; j < 16; j++) { aq[j] += a * pq[j]; ak[j] += a * pk[j]; av[j] += a * pv[j]; }
    }
    #pragma unroll
    for (int j = 0; j < 16; j++) { qs[n * 65 + d0 + j] = aq[j]; ks_[n * 65 + d0 + j] = ak[j]; vs[n * 65 + d0 + j] = av[j]; }
  }
  __syncthreads();

  // 3. attention: thread = (head = tid>>6, i = tid&63)
  {
    int head = tid >> 6, i = tid & 63;
    float qv[16];
    #pragma unroll
    for (int j = 0; j < 16; j++) qv[j] = qs[i * 65 + head * 16 + j];
    float sc[64]; float m = -1e30f;
    #pragma unroll
    for (int jn = 0; jn < 64; jn++) {
      float d = 0.f;
      const float* kr = &ks_[jn * 65 + head * 16];
      #pragma unroll
      for (int j = 0; j < 16; j++) d += qv[j] * kr[j];
      d = d * 0.25f + bias[i * 64 + jn];
      sc[jn] = d; m = fmaxf(m, d);
    }
    float sum = 0.f;
    #pragma unroll
    for (int jn = 0; jn < 64; jn++) { float e = expf(sc[jn] - m); sc[jn] = e; sum += e; }
    float inv = 1.0f / sum;
    float oacc[16];
    #pragma unroll
    for (int j = 0; j < 16; j++) oacc[j] = 0.f;
    #pragma unroll
    for (int jn = 0; jn < 64; jn++) {
      float a = sc[jn] * inv;
      const float* vr = &vs[jn * 65 + head * 16];
      #pragma unroll
      for (int j = 0; j < 16; j++) oacc[j] += a * vr[j];
    }
    #pragma unroll
    for (int j = 0; j < 16; j++) os_[i * 65 + head * 16 + j] = oacc[j];
  }
  __syncthreads();

  // 4. o @ Wo + bo, residual -> xs
  {
    int n = tid >> 2, d0 = (tid & 3) << 4;
    float acc[16];
    #pragma unroll
    for (int j = 0; j < 16; j++) acc[j] = bo[l * 64 + d0 + j];
    for (int kk = 0; kk < 64; kk++) {
      float a = os_[n * 65 + kk];
      const float* pw = &wo[kk * 64 + d0];
      #pragma unroll
      for (int j = 0; j < 16; j++) acc[j] += a * pw[j];
    }
    #pragma unroll
    for (int j = 0; j < 16; j++) xs[n * 65 + d0 + j] = hs[n * 65 + d0 + j] + r1 * acc[j];
  }
  __syncthreads();

  // 5. LN1 -> hs
  if (tid < 64) {
    float s = 0.f, s2 = 0.f;
    for (int j = 0; j < 64; j++) { float v = xs[tid * 65 + j]; s += v; s2 += v * v; }
    float mean = s * 0.015625f, var = s2 * 0.015625f - mean * mean;
    mv[tid * 2] = mean; mv[tid * 2 + 1] = rsqrtf(var + 1e-5f);
  }
  __syncthreads();
  for (int idx = tid; idx < 4096; idx += 256) {
    int n = idx >> 6, d = idx & 63;
    hs[n * 65 + d] = (xs[n * 65 + d] - mv[n * 2]) * mv[n * 2 + 1] * ln1g[l * 64 + d] + ln1b[l * 64 + d];
  }
  __syncthreads();

  // 6. FFN1: gs = gelu(hs @ W1 + b1)   (thread: n = tid>>2, 64 cols at (tid&3)*64)
  {
    int n = tid >> 2, j0 = (tid & 3) << 6;
    float acc[64];
    #pragma unroll
    for (int j = 0; j < 64; j++) acc[j] = b1[l * 256 + j0 + j];
    for (int kk = 0; kk < 64; kk++) {
      float a = hs[n * 65 + kk];
      const float* pw = &w1[kk * 256 + j0];
      #pragma unroll
      for (int j = 0; j < 64; j++) acc[j] += a * pw[j];
    }
    #pragma unroll
    for (int j = 0; j < 64; j++) {
      float xg = acc[j];
      float u = 0.7978845608028654f * (xg + 0.044715f * xg * xg * xg);
      gs[n * 257 + j0 + j] = 0.5f * xg * (1.0f + tanhf(u));
    }
  }
  __syncthreads();

  // 7. FFN2 + residual -> xs
  {
    int n = tid >> 2, d0 = (tid & 3) << 4;
    float acc[16];
    #pragma unroll
    for (int j = 0; j < 16; j++) acc[j] = b2[l * 64 + d0 + j];
    for (int kk = 0; kk < 256; kk++) {
      float a = gs[n * 257 + kk];
      const float* pw = &w2[kk * 64 + d0];
      #pragma unroll
      for (int j = 0; j < 16; j++) acc[j] += a * pw[j];
    }
    #pragma unroll
    for (int j = 0; j < 16; j++) xs[n * 65 + d0 + j] = hs[n * 65 + d0 + j] + r2 * acc[j];
  }
  __syncthreads();

  // 8. LN2 -> global h
  if (tid < 64) {
    float s = 0.f, s2 = 0.f;
    for (int j = 0; j < 64; j++) { float v = xs[tid * 65 + j]; s += v; s2 += v * v; }
    float mean = s * 0.015625f, var = s2 * 0.015625f - mean * mean;
    mv[tid * 2] = mean; mv[tid * 2 + 1] = rsqrtf(var + 1e-5f);
  }
  __syncthreads();
  for (int idx = tid; idx < 4096; idx += 256) {
    int n = idx >> 6, d = idx & 63;
    hbuf[base + idx] = (xs[n * 65 + d] - mv[n * 2]) * mv[n * 2 + 1] * ln2g[l * 64 + d] + ln2b[l * 64 + d];
  }
}

// ---------- k_transpose: lin_w [16384][4096] f32 -> wt [4096][16384] bf16 ----------
__global__ void k_transpose(const float* __restrict__ w, unsigned short* __restrict__ wt) {
  __shared__ float tile[64][65];
  int bk = blockIdx.x & 255;   // 256 k-tiles
  int bn = blockIdx.x >> 8;    // 64 n-tiles
  int tid = threadIdx.x;
  int c = tid & 63, r0 = tid >> 6;
  #pragma unroll
  for (int i = 0; i < 16; i++) {
    int r = r0 + i * 4;
    tile[r][c] = w[((size_t)(bk * 64 + r)) * 4096 + bn * 64 + c];
  }
  __syncthreads();
  #pragma unroll
  for (int i = 0; i < 16; i++) {
    int r = r0 + i * 4;
    wt[((size_t)(bn * 64 + r)) * 16384 + bk * 64 + c] = f2bf(tile[c][r]);
  }
}

// ---------- k_packA: h[b,t,n,d] -> A_bf16[(b*64+n)][t*64+d] ----------
__global__ void k_packA(const float* __restrict__ hbuf, unsigned short* __restrict__ A) {
  size_t idx = (size_t)blockIdx.x * 256 + threadIdx.x;  // 16,777,216 total
  float v = hbuf[idx];
  int d = (int)(idx & 63), node = (int)((idx >> 6) & 63);
  int t = (int)((idx >> 12) & 255), b = (int)(idx >> 20);
  A[(((size_t)b * 64 + node) << 14) + t * 64 + d] = f2bf(v);
}

// ---------- k_gemm: out[b,l,n] = A[1024x16384] @ lin_w[16384x4096] + lin_b ----------
__global__ __launch_bounds__(256, 1) void k_gemm(const unsigned short* __restrict__ A,
                                                 const unsigned short* __restrict__ Bt,
                                                 const float* __restrict__ lin_b,
                                                 float* __restrict__ out) {
  __shared__ unsigned short As[128 * 64];
  __shared__ unsigned short Bs[128 * 64];
  const int tid = threadIdx.x;
  const int lane = tid & 63;
  const int wv = tid >> 6;
  const int bm = blockIdx.x >> 5;   // 8 M-tiles
  const int bn = blockIdx.x & 31;   // 32 N-tiles
  const int m0 = bm << 7, n0 = bn << 7;
  f32x4 acc[4][4];
  #pragma unroll
  for (int i = 0; i < 4; i++)
    #pragma unroll
    for (int j = 0; j < 4; j++) acc[i][j] = f32x4{0.f, 0.f, 0.f, 0.f};

  const int r15 = lane & 15;
  const int kg = (lane >> 4) << 3;
  const int wm = wv >> 1, wn = wv & 1;

  for (int kt = 0; kt < 256; kt++) {
    const unsigned short* ab = A  + ((size_t)m0 << 14) + (kt << 6);
    const unsigned short* bb = Bt + ((size_t)n0 << 14) + (kt << 6);
    #pragma unroll
    for (int j = 0; j < 4; j++) {
      int c = ((wv * 4 + j) << 6) + lane;   // 16B chunk index 0..1023
      __builtin_amdgcn_global_load_lds(AS1(ab + ((size_t)(c >> 3) << 14) + ((c & 7) << 3)),
                                       AS3(&As[(wv * 4 + j) << 9]), 16, 0, 0);
      __builtin_amdgcn_global_load_lds(AS1(bb + ((size_t)(c >> 3) << 14) + ((c & 7) << 3)),
                                       AS3(&Bs[(wv * 4 + j) << 9]), 16, 0, 0);
    }
    __syncthreads();
    #pragma unroll
    for (int ks = 0; ks < 2; ks++) {
      bf16x8 af[4], bfr[4];
      #pragma unroll
      for (int mi = 0; mi < 4; mi++)
        af[mi] = *(const bf16x8*)&As[(wm << 12) + ((mi * 16 + r15) << 6) + (ks << 5) + kg];
      #pragma unroll
      for (int ni = 0; ni < 4; ni++)
        bfr[ni] = *(const bf16x8*)&Bs[(wn << 12) + ((ni * 16 + r15) << 6) + (ks << 5) + kg];
      #pragma unroll
      for (int mi = 0; mi < 4; mi++)
        #pragma unroll
        for (int ni = 0; ni < 4; ni++)
          acc[mi][ni] = __builtin_amdgcn_mfma_f32_16x16x32_bf16(af[mi], bfr[ni], acc[mi][ni], 0, 0, 0);
    }
    __syncthreads();
  }

  // epilogue: C row m=(b*64+node), col l -> out[(b*4096+l)*64+node], + lin_b
  #pragma unroll
  for (int mi = 0; mi < 4; mi++) {
    #pragma unroll
    for (int ni = 0; ni < 4; ni++) {
      int col = n0 + (wn << 6) + ni * 16 + r15;
      float lb = lin_b[col];
      #pragma unroll
      for (int j = 0; j < 4; j++) {
        int row = m0 + (wm << 6) + mi * 16 + ((lane >> 4) << 2) + j;
        out[(((size_t)(row >> 6) << 12) + col) * 64 + (row & 63)] = acc[mi][ni][j] + lb;
      }
    }
  }
}

// ---------- launch ----------
extern "C" void kernel_launch(void* const* d_in, const int* in_sizes, int n_in,
                              void* d_out, int out_size, void* d_ws, size_t ws_size,
                              hipStream_t stream) {
  const float* x      = (const float*)d_in[0];
  const float* emb    = (const float*)d_in[1];
  const float* conv_w = (const float*)d_in[2];
  const float* conv_b = (const float*)d_in[3];
  const float* Wq = (const float*)d_in[4],  *bq = (const float*)d_in[5];
  const float* Wk = (const float*)d_in[6],  *bk = (const float*)d_in[7];
  const float* Wv = (const float*)d_in[8],  *bv = (const float*)d_in[9];
  const float* Wo = (const float*)d_in[10], *bo = (const float*)d_in[11];
  const float* ln1g = (const float*)d_in[12], *ln1b = (const float*)d_in[13];
  const float* ln2g = (const float*)d_in[14], *ln2b = (const float*)d_in[15];
  const float* W1 = (const float*)d_in[16], *b1 = (const float*)d_in[17];
  const float* W2 = (const float*)d_in[18], *b2 = (const float*)d_in[19];
  const float* res1 = (const float*)d_in[20], *res2 = (const float*)d_in[21];
  const float* lin_w = (const float*)d_in[22], *lin_b = (const float*)d_in[23];
  float* out = (float*)d_out;

  char* ws = (char*)d_ws;
  float* bias            = (float*)ws;                          //    16,384 B
  float* hbuf            = (float*)(ws + 16384);                // 67,108,864 B
  unsigned short* wt     = (unsigned short*)(ws + 16384 + 67108864);            // 134,217,728 B
  unsigned short* Abf    = (unsigned short*)(ws + 16384 + 67108864 + 134217728); // 33,554,432 B
  // total ws use: 234,897,408 B

  k_bias<<<1, 64, 0, stream>>>(emb, bias);
  k_conv<<<4096, 256, 0, stream>>>(x, conv_w, conv_b, hbuf);
  k_transpose<<<16384, 256, 0, stream>>>(lin_w, wt);
  for (int l = 0; l < 2; l++)
    k_layer<<<4096, 256, 0, stream>>>(hbuf, emb, bias, Wq, bq, Wk, bk, Wv, bv, Wo, bo,
                                      ln1g, ln1b, ln2g, ln2b, W1, b1, W2, b2, res1, res2, l);
  k_packA<<<65536, 256, 0, stream>>>(hbuf, Abf);
  k_gemm<<<256, 256, 0, stream>>>(Abf, wt, lin_b, out);
}

// Round 4
// 1095.421 us; speedup vs baseline: 7.9541x; 7.9541x over previous
//
#include <hip/hip_runtime.h>
#include <hip/hip_bf16.h>
#include <stdint.h>

// ---------- helpers ----------
#define AS1(p) ((const __attribute__((address_space(1))) void*)(p))
#define AS3(p) ((__attribute__((address_space(3))) void*)(p))

typedef __bf16 bf16x8 __attribute__((ext_vector_type(8)));
typedef float f32x4 __attribute__((ext_vector_type(4)));
typedef unsigned short u16;

#define MFMA(a, b, cc) __builtin_amdgcn_mfma_f32_16x16x32_bf16(a, b, cc, 0, 0, 0)

__device__ __forceinline__ u16 f2bf(float f) {
  unsigned u = __builtin_bit_cast(unsigned, f);
  u = (u + 0x7FFFu + ((u >> 16) & 1u)) >> 16;   // RNE
  return (u16)u;
}

// ---------- constants ----------
// B=16 L=4096 N=64 D=64 H=4 WAVE=16 T=256 DFF=256 DH=16 TOPK=16

// ---------- k_bias ----------
__global__ void k_bias(const float* __restrict__ emb, float* __restrict__ bias) {
  __shared__ float e[64 * 64];
  __shared__ float nrm[64];
  __shared__ float cosr[64 * 65];
  int tid = threadIdx.x;  // 64 threads
  for (int idx = tid; idx < 4096; idx += 64) e[idx] = emb[idx];
  __syncthreads();
  float s = 0.f;
  for (int j = 0; j < 64; j++) { float v = e[tid * 64 + j]; s += v * v; }
  nrm[tid] = sqrtf(s);
  __syncthreads();
  for (int jj = 0; jj < 64; jj++) {
    float d = 0.f;
    for (int kk = 0; kk < 64; kk++) d += e[tid * 64 + kk] * e[jj * 64 + kk];
    cosr[tid * 65 + jj] = d / (nrm[tid] * nrm[jj]);
  }
  unsigned long long sel = 0ull;
  for (int it = 0; it < 16; it++) {
    float best = -1e30f; int bi = 0;
    for (int j = 0; j < 64; j++) {
      if ((sel >> j) & 1ull) continue;
      float c = cosr[tid * 65 + j];
      if (c > best) { best = c; bi = j; }
    }
    sel |= (1ull << bi);
  }
  for (int j = 0; j < 64; j++)
    bias[tid * 64 + j] = ((sel >> j) & 1ull) ? 0.0f : -1e9f;
}

// ---------- k_conv ----------
__global__ void k_conv(const float* __restrict__ x, const float* __restrict__ conv_w,
                       const float* __restrict__ conv_b, float* __restrict__ h) {
  int bt = blockIdx.x;
  int b = bt >> 8, t = bt & 255;
  __shared__ float xs[16 * 64];
  int tid = threadIdx.x;
  for (int idx = tid; idx < 1024; idx += 256)
    xs[idx] = x[((size_t)b * 4096 + t * 16 + (idx >> 6)) * 64 + (idx & 63)];
  __syncthreads();
  int d = tid & 63, n0 = (tid >> 6) << 4;
  float xv[16];
  #pragma unroll
  for (int w = 0; w < 16; w++) xv[w] = xs[w * 64 + d];
  for (int n = n0; n < n0 + 16; n++) {
    float acc = conv_b[d * 64 + n];
    const float* wp = &conv_w[(d * 64 + n) * 16];
    #pragma unroll
    for (int w = 0; w < 16; w++) acc += xv[w] * wp[w];
    h[((size_t)bt * 64 + n) * 64 + d] = acc;
  }
}

// ---------- k_wprep: transpose weights -> bf16 [n][k] ----------
__global__ void k_wprep(const float* __restrict__ Wq, const float* __restrict__ Wk,
                        const float* __restrict__ Wv, const float* __restrict__ Wo,
                        const float* __restrict__ W1, const float* __restrict__ W2,
                        u16* __restrict__ WqT, u16* __restrict__ WkT,
                        u16* __restrict__ WvT, u16* __restrict__ WoT,
                        u16* __restrict__ W1T, u16* __restrict__ W2T) {
  int e = blockIdx.x * 256 + threadIdx.x;   // 98304 total
  int l = e / 49152, r = e % 49152;
  if (r < 16384) {
    int mat = r >> 12, i = r & 4095, n = i >> 6, k = i & 63;
    const float* W = mat == 0 ? Wq : mat == 1 ? Wk : mat == 2 ? Wv : Wo;
    u16* WT = mat == 0 ? WqT : mat == 1 ? WkT : mat == 2 ? WvT : WoT;
    WT[l * 4096 + i] = f2bf(W[l * 4096 + k * 64 + n]);
  } else if (r < 32768) {
    int i = r - 16384, n = i >> 6, k = i & 63;
    W1T[l * 16384 + i] = f2bf(W1[l * 16384 + k * 256 + n]);
  } else {
    int i = r - 32768, n = i >> 8, k = i & 255;
    W2T[l * 16384 + i] = f2bf(W2[l * 16384 + k * 64 + n]);
  }
}

// ---------- k_layer2: fused MFMA transformer layer, one (b,t) per block ----------
// LDS map (bytes):
//   hres f32 [64][68]   @ 0      (17408)  residual stream (kept fp32)
//   act  bf16 [64][72]  @ 17408  (9216)   GEMM A-operand staging
//   qb   bf16 [64][136] @ 26624  (17408)  per-head 32-wide, upper 16 zero
//   kb   bf16 [64][136] @ 44032  (17408)
//   vtb  bf16 [64][72]  @ 61440  (9216)   v transposed [dh][node]
//   pb   bf16 [64][72]  @ 70656  (9216)   probs (per-wave rows)
//   gb   bf16 [64][264] overlays qb+kb    (33792 <= 34816)
// total 79872 B -> 2 blocks/CU
__global__ __launch_bounds__(256, 2) void k_layer2(
    float* __restrict__ hbuf, const float* __restrict__ emb, const float* __restrict__ bias,
    const u16* __restrict__ WqT, const u16* __restrict__ WkT,
    const u16* __restrict__ WvT, const u16* __restrict__ WoT,
    const u16* __restrict__ W1T, const u16* __restrict__ W2T,
    const float* __restrict__ bq, const float* __restrict__ bk,
    const float* __restrict__ bv, const float* __restrict__ bo,
    const float* __restrict__ ln1g, const float* __restrict__ ln1b,
    const float* __restrict__ ln2g, const float* __restrict__ ln2b,
    const float* __restrict__ b1, const float* __restrict__ b2,
    const float* __restrict__ r1p, const float* __restrict__ r2p) {
  __shared__ __align__(16) unsigned char smem[79872];
  float* hres = (float*)smem;
  u16* act = (u16*)(smem + 17408);
  u16* qb  = (u16*)(smem + 26624);
  u16* kb  = (u16*)(smem + 44032);
  u16* vtb = (u16*)(smem + 61440);
  u16* pb  = (u16*)(smem + 70656);
  u16* gb  = (u16*)(smem + 26624);

  const int tid = threadIdx.x;
  const int w = tid >> 6, lane = tid & 63;
  const int g = lane >> 4, c = lane & 15;
  const size_t base = (size_t)blockIdx.x << 12;
  const float r1 = *r1p, r2 = *r2p;

  // phase 1: load h, hin = h+emb -> act(bf16); zero qb/kb
  #pragma unroll
  for (int i = 0; i < 4; i++) {
    int v = tid + (i << 8);
    f32x4 hv = ((const f32x4*)(hbuf + base))[v];
    f32x4 ev = ((const f32x4*)emb)[v];
    int n = v >> 4, d = (v & 15) << 2;
    *(f32x4*)&hres[n * 68 + d] = hv;
    ushort4 u;
    u.x = f2bf(hv[0] + ev[0]); u.y = f2bf(hv[1] + ev[1]);
    u.z = f2bf(hv[2] + ev[2]); u.w = f2bf(hv[3] + ev[3]);
    *(ushort4*)&act[n * 72 + d] = u;
  }
  for (int i = tid; i < 2176; i += 256) {
    f32x4 z; z[0] = 0.f; z[1] = 0.f; z[2] = 0.f; z[3] = 0.f;
    ((f32x4*)(smem + 26624))[i] = z;
  }
  __syncthreads();   // bar1

  bf16x8 af[4][2];
  auto load_af_act = [&]() {
    #pragma unroll
    for (int rt = 0; rt < 4; rt++)
      #pragma unroll
      for (int ks = 0; ks < 2; ks++)
        af[rt][ks] = *(const bf16x8*)&act[(rt * 16 + c) * 72 + ks * 32 + g * 8];
  };
  auto gemm64 = [&](const u16* __restrict__ Wt, f32x4 acc[4]) {
    #pragma unroll
    for (int rt = 0; rt < 4; rt++) { acc[rt][0] = 0.f; acc[rt][1] = 0.f; acc[rt][2] = 0.f; acc[rt][3] = 0.f; }
    #pragma unroll
    for (int ks = 0; ks < 2; ks++) {
      bf16x8 bw = *(const bf16x8*)&Wt[(w * 16 + c) * 64 + ks * 32 + g * 8];
      #pragma unroll
      for (int rt = 0; rt < 4; rt++) acc[rt] = MFMA(af[rt][ks], bw, acc[rt]);
    }
  };

  // phase 2: QKV (col-split: wave w owns cols/head w)
  load_af_act();
  {
    f32x4 aq[4], ak[4], av[4];
    gemm64(WqT, aq); gemm64(WkT, ak); gemm64(WvT, av);
    float bqv = bq[w * 16 + c], bkv = bk[w * 16 + c], bvv = bv[w * 16 + c];
    #pragma unroll
    for (int rt = 0; rt < 4; rt++) {
      #pragma unroll
      for (int jj = 0; jj < 4; jj++) {
        int row = rt * 16 + g * 4 + jj;
        qb[row * 136 + w * 32 + c] = f2bf(aq[rt][jj] + bqv);
        kb[row * 136 + w * 32 + c] = f2bf(ak[rt][jj] + bkv);
      }
      ushort4 pv;
      pv.x = f2bf(av[rt][0] + bvv); pv.y = f2bf(av[rt][1] + bvv);
      pv.z = f2bf(av[rt][2] + bvv); pv.w = f2bf(av[rt][3] + bvv);
      *(ushort4*)&vtb[(w * 16 + c) * 72 + rt * 16 + g * 4] = pv;
    }
  }
  __syncthreads();   // bar2

  // phase 3: attention (row-split: wave w owns query rows 16w..16w+15)
  {
    float bias_r[4][4];
    #pragma unroll
    for (int jj = 0; jj < 4; jj++)
      #pragma unroll
      for (int ct = 0; ct < 4; ct++)
        bias_r[jj][ct] = bias[(w * 16 + g * 4 + jj) * 64 + ct * 16 + c];

    #pragma unroll
    for (int h = 0; h < 4; h++) {
      bf16x8 aq = *(const bf16x8*)&qb[(w * 16 + c) * 136 + h * 32 + g * 8];
      f32x4 sacc[4];
      #pragma unroll
      for (int ct = 0; ct < 4; ct++) { sacc[ct][0]=0.f; sacc[ct][1]=0.f; sacc[ct][2]=0.f; sacc[ct][3]=0.f; }
      #pragma unroll
      for (int ct = 0; ct < 4; ct++) {
        bf16x8 bk8 = *(const bf16x8*)&kb[(ct * 16 + c) * 136 + h * 32 + g * 8];
        sacc[ct] = MFMA(aq, bk8, sacc[ct]);
      }
      #pragma unroll
      for (int jj = 0; jj < 4; jj++) {
        float s0 = sacc[0][jj] * 0.25f + bias_r[jj][0];
        float s1 = sacc[1][jj] * 0.25f + bias_r[jj][1];
        float s2 = sacc[2][jj] * 0.25f + bias_r[jj][2];
        float s3 = sacc[3][jj] * 0.25f + bias_r[jj][3];
        float m = fmaxf(fmaxf(s0, s1), fmaxf(s2, s3));
        m = fmaxf(m, __shfl_xor(m, 1)); m = fmaxf(m, __shfl_xor(m, 2));
        m = fmaxf(m, __shfl_xor(m, 4)); m = fmaxf(m, __shfl_xor(m, 8));
        float e0 = __expf(s0 - m), e1 = __expf(s1 - m), e2 = __expf(s2 - m), e3 = __expf(s3 - m);
        float sum = e0 + e1 + e2 + e3;
        sum += __shfl_xor(sum, 1); sum += __shfl_xor(sum, 2);
        sum += __shfl_xor(sum, 4); sum += __shfl_xor(sum, 8);
        float inv = 1.0f / sum;
        int prow = w * 16 + g * 4 + jj;
        pb[prow * 72 +  0 + c] = f2bf(e0 * inv);
        pb[prow * 72 + 16 + c] = f2bf(e1 * inv);
        pb[prow * 72 + 32 + c] = f2bf(e2 * inv);
        pb[prow * 72 + 48 + c] = f2bf(e3 * inv);
      }
      // fence: pb written as u16 scalars, read below as bf16x8
      __syncthreads();
      f32x4 oacc; oacc[0]=0.f; oacc[1]=0.f; oacc[2]=0.f; oacc[3]=0.f;
      #pragma unroll
      for (int ks = 0; ks < 2; ks++) {
        bf16x8 ap  = *(const bf16x8*)&pb[(w * 16 + c) * 72 + ks * 32 + g * 8];
        bf16x8 bv8 = *(const bf16x8*)&vtb[(h * 16 + c) * 72 + ks * 32 + g * 8];
        oacc = MFMA(ap, bv8, oacc);
      }
      // fence: next head's pb writes must not precede this head's reads
      __syncthreads();
      #pragma unroll
      for (int jj = 0; jj < 4; jj++)
        act[(w * 16 + g * 4 + jj) * 72 + h * 16 + c] = f2bf(oacc[jj]);
    }
  }
  __syncthreads();   // bar3

  // phase 4: proj + residual (col-split)
  load_af_act();
  {
    f32x4 po[4];
    gemm64(WoT, po);
    float bov = bo[w * 16 + c];
    #pragma unroll
    for (int rt = 0; rt < 4; rt++)
      #pragma unroll
      for (int jj = 0; jj < 4; jj++) {
        int idx = (rt * 16 + g * 4 + jj) * 68 + w * 16 + c;
        hres[idx] += r1 * (po[rt][jj] + bov);
      }
  }
  __syncthreads();   // bar4

  // phase 5: LN1 (wave-local rows) -> act (bf16, FFN input) AND hres (fp32 residual!)
  // BUGFIX r3: reference's second residual uses POST-LN1 h; hres must be updated.
  {
    int row = w * 16 + (lane >> 2), c0 = (lane & 3) << 4;
    float s = 0.f, s2 = 0.f;
    #pragma unroll
    for (int jv = 0; jv < 4; jv++) {
      f32x4 v = *(const f32x4*)&hres[row * 68 + c0 + jv * 4];
      s += v[0] + v[1] + v[2] + v[3];
      s2 += v[0]*v[0] + v[1]*v[1] + v[2]*v[2] + v[3]*v[3];
    }
    s += __shfl_xor(s, 1);  s += __shfl_xor(s, 2);
    s2 += __shfl_xor(s2, 1); s2 += __shfl_xor(s2, 2);
    float mean = s * 0.015625f, var = s2 * 0.015625f - mean * mean;
    float rstd = rsqrtf(var + 1e-5f);
    #pragma unroll
    for (int j = 0; j < 16; j++) {
      float val = (hres[row * 68 + c0 + j] - mean) * rstd * ln1g[c0 + j] + ln1b[c0 + j];
      act[row * 72 + c0 + j] = f2bf(val);
      hres[row * 68 + c0 + j] = val;
    }
  }
  __syncthreads();   // bar5

  // phase 6: FFN1 (col-split, wave w cols 64w..64w+63) -> gb (overlays qb/kb)
  load_af_act();
  #pragma unroll
  for (int half = 0; half < 2; half++) {
    f32x4 fa[2][4];
    #pragma unroll
    for (int ci = 0; ci < 2; ci++)
      #pragma unroll
      for (int rt = 0; rt < 4; rt++) { fa[ci][rt][0]=0.f; fa[ci][rt][1]=0.f; fa[ci][rt][2]=0.f; fa[ci][rt][3]=0.f; }
    #pragma unroll
    for (int ci = 0; ci < 2; ci++) {
      int n0 = w * 64 + half * 32 + ci * 16;
      #pragma unroll
      for (int ks = 0; ks < 2; ks++) {
        bf16x8 bw = *(const bf16x8*)&W1T[(n0 + c) * 64 + ks * 32 + g * 8];
        #pragma unroll
        for (int rt = 0; rt < 4; rt++) fa[ci][rt] = MFMA(af[rt][ks], bw, fa[ci][rt]);
      }
    }
    #pragma unroll
    for (int ci = 0; ci < 2; ci++) {
      int col = w * 64 + half * 32 + ci * 16 + c;
      float b1v = b1[col];
      #pragma unroll
      for (int rt = 0; rt < 4; rt++)
        #pragma unroll
        for (int jj = 0; jj < 4; jj++) {
          float xg = fa[ci][rt][jj] + b1v;
          float u2 = 1.5957691216057308f * (xg + 0.044715f * xg * xg * xg);
          float t = 1.f - 2.f / (1.f + __expf(u2));
          gb[(rt * 16 + g * 4 + jj) * 264 + col] = f2bf(0.5f * xg * (1.f + t));
        }
    }
  }
  __syncthreads();   // bar6

  // phase 7: FFN2 + residual (col-split)
  {
    f32x4 a2[4];
    #pragma unroll
    for (int rt = 0; rt < 4; rt++) { a2[rt][0]=0.f; a2[rt][1]=0.f; a2[rt][2]=0.f; a2[rt][3]=0.f; }
    #pragma unroll
    for (int ks = 0; ks < 8; ks++) {
      bf16x8 bw = *(const bf16x8*)&W2T[(w * 16 + c) * 256 + ks * 32 + g * 8];
      #pragma unroll
      for (int rt = 0; rt < 4; rt++) {
        bf16x8 ag = *(const bf16x8*)&gb[(rt * 16 + c) * 264 + ks * 32 + g * 8];
        a2[rt] = MFMA(ag, bw, a2[rt]);
      }
    }
    float b2v = b2[w * 16 + c];
    #pragma unroll
    for (int rt = 0; rt < 4; rt++)
      #pragma unroll
      for (int jj = 0; jj < 4; jj++) {
        int idx = (rt * 16 + g * 4 + jj) * 68 + w * 16 + c;
        hres[idx] += r2 * (a2[rt][jj] + b2v);
      }
  }
  __syncthreads();   // bar7

  // phase 8: LN2 (wave-local rows) -> global
  {
    int row = w * 16 + (lane >> 2), c0 = (lane & 3) << 4;
    float s = 0.f, s2 = 0.f;
    #pragma unroll
    for (int jv = 0; jv < 4; jv++) {
      f32x4 v = *(const f32x4*)&hres[row * 68 + c0 + jv * 4];
      s += v[0] + v[1] + v[2] + v[3];
      s2 += v[0]*v[0] + v[1]*v[1] + v[2]*v[2] + v[3]*v[3];
    }
    s += __shfl_xor(s, 1);  s += __shfl_xor(s, 2);
    s2 += __shfl_xor(s2, 1); s2 += __shfl_xor(s2, 2);
    float mean = s * 0.015625f, var = s2 * 0.015625f - mean * mean;
    float rstd = rsqrtf(var + 1e-5f);
    #pragma unroll
    for (int jv = 0; jv < 4; jv++) {
      f32x4 v = *(const f32x4*)&hres[row * 68 + c0 + jv * 4];
      f32x4 o;
      #pragma unroll
      for (int e = 0; e < 4; e++)
        o[e] = (v[e] - mean) * rstd * ln2g[c0 + jv * 4 + e] + ln2b[c0 + jv * 4 + e];
      *(f32x4*)&hbuf[base + row * 64 + c0 + jv * 4] = o;
    }
  }
}

// ---------- k_transpose: lin_w [16384][4096] f32 -> wt [4096][16384] bf16 ----------
__global__ void k_transpose(const float* __restrict__ w, u16* __restrict__ wt) {
  __shared__ float tile[64][65];
  int bk = blockIdx.x & 255;
  int bn = blockIdx.x >> 8;
  int tid = threadIdx.x;
  int c = tid & 63, r0 = tid >> 6;
  #pragma unroll
  for (int i = 0; i < 16; i++) {
    int r = r0 + i * 4;
    tile[r][c] = w[((size_t)(bk * 64 + r)) * 4096 + bn * 64 + c];
  }
  __syncthreads();
  #pragma unroll
  for (int i = 0; i < 16; i++) {
    int r = r0 + i * 4;
    wt[((size_t)(bn * 64 + r)) * 16384 + bk * 64 + c] = f2bf(tile[c][r]);
  }
}

// ---------- k_packA ----------
__global__ void k_packA(const float* __restrict__ hbuf, u16* __restrict__ A) {
  size_t idx = (size_t)blockIdx.x * 256 + threadIdx.x;
  float v = hbuf[idx];
  int d = (int)(idx & 63), node = (int)((idx >> 6) & 63);
  int t = (int)((idx >> 12) & 255), b = (int)(idx >> 20);
  A[(((size_t)b * 64 + node) << 14) + t * 64 + d] = f2bf(v);
}

// ---------- k_gemm ----------
__global__ __launch_bounds__(256, 1) void k_gemm(const u16* __restrict__ A,
                                                 const u16* __restrict__ Bt,
                                                 const float* __restrict__ lin_b,
                                                 float* __restrict__ out) {
  __shared__ u16 As[128 * 64];
  __shared__ u16 Bs[128 * 64];
  const int tid = threadIdx.x;
  const int lane = tid & 63;
  const int wv = tid >> 6;
  const int bm = blockIdx.x >> 5;
  const int bn = blockIdx.x & 31;
  const int m0 = bm << 7, n0 = bn << 7;
  f32x4 acc[4][4];
  #pragma unroll
  for (int i = 0; i < 4; i++)
    #pragma unroll
    for (int j = 0; j < 4; j++) { acc[i][j][0]=0.f; acc[i][j][1]=0.f; acc[i][j][2]=0.f; acc[i][j][3]=0.f; }

  const int r15 = lane & 15;
  const int kg = (lane >> 4) << 3;
  const int wm = wv >> 1, wn = wv & 1;

  for (int kt = 0; kt < 256; kt++) {
    const u16* ab = A  + ((size_t)m0 << 14) + (kt << 6);
    const u16* bb = Bt + ((size_t)n0 << 14) + (kt << 6);
    #pragma unroll
    for (int j = 0; j < 4; j++) {
      int cix = ((wv * 4 + j) << 6) + lane;
      __builtin_amdgcn_global_load_lds(AS1(ab + ((size_t)(cix >> 3) << 14) + ((cix & 7) << 3)),
                                       AS3(&As[(wv * 4 + j) << 9]), 16, 0, 0);
      __builtin_amdgcn_global_load_lds(AS1(bb + ((size_t)(cix >> 3) << 14) + ((cix & 7) << 3)),
                                       AS3(&Bs[(wv * 4 + j) << 9]), 16, 0, 0);
    }
    __syncthreads();
    #pragma unroll
    for (int ks = 0; ks < 2; ks++) {
      bf16x8 af2[4], bfr[4];
      #pragma unroll
      for (int mi = 0; mi < 4; mi++)
        af2[mi] = *(const bf16x8*)&As[(wm << 12) + ((mi * 16 + r15) << 6) + (ks << 5) + kg];
      #pragma unroll
      for (int ni = 0; ni < 4; ni++)
        bfr[ni] = *(const bf16x8*)&Bs[(wn << 12) + ((ni * 16 + r15) << 6) + (ks << 5) + kg];
      #pragma unroll
      for (int mi = 0; mi < 4; mi++)
        #pragma unroll
        for (int ni = 0; ni < 4; ni++)
          acc[mi][ni] = MFMA(af2[mi], bfr[ni], acc[mi][ni]);
    }
    __syncthreads();
  }

  #pragma unroll
  for (int mi = 0; mi < 4; mi++) {
    #pragma unroll
    for (int ni = 0; ni < 4; ni++) {
      int col = n0 + (wn << 6) + ni * 16 + r15;
      float lb = lin_b[col];
      #pragma unroll
      for (int j = 0; j < 4; j++) {
        int row = m0 + (wm << 6) + mi * 16 + ((lane >> 4) << 2) + j;
        out[(((size_t)(row >> 6) << 12) + col) * 64 + (row & 63)] = acc[mi][ni][j] + lb;
      }
    }
  }
}

// ---------- launch ----------
extern "C" void kernel_launch(void* const* d_in, const int* in_sizes, int n_in,
                              void* d_out, int out_size, void* d_ws, size_t ws_size,
                              hipStream_t stream) {
  const float* x      = (const float*)d_in[0];
  const float* emb    = (const float*)d_in[1];
  const float* conv_w = (const float*)d_in[2];
  const float* conv_b = (const float*)d_in[3];
  const float* Wq = (const float*)d_in[4],  *bq = (const float*)d_in[5];
  const float* Wk = (const float*)d_in[6],  *bk = (const float*)d_in[7];
  const float* Wv = (const float*)d_in[8],  *bv = (const float*)d_in[9];
  const float* Wo = (const float*)d_in[10], *bo = (const float*)d_in[11];
  const float* ln1g = (const float*)d_in[12], *ln1b = (const float*)d_in[13];
  const float* ln2g = (const float*)d_in[14], *ln2b = (const float*)d_in[15];
  const float* W1 = (const float*)d_in[16], *b1 = (const float*)d_in[17];
  const float* W2 = (const float*)d_in[18], *b2 = (const float*)d_in[19];
  const float* res1 = (const float*)d_in[20], *res2 = (const float*)d_in[21];
  const float* lin_w = (const float*)d_in[22], *lin_b = (const float*)d_in[23];
  float* out = (float*)d_out;

  char* ws = (char*)d_ws;
  float* bias   = (float*)ws;                                        //    16,384 B
  float* hbuf   = (float*)(ws + 16384);                              // 67,108,864 B
  u16*   wt     = (u16*)(ws + 16384 + 67108864);                     // 134,217,728 B
  u16*   Abf    = (u16*)(ws + 16384 + 67108864 + 134217728);         // 33,554,432 B
  // WT region overlays Abf (time-disjoint: wprep->layers use it, packA overwrites after)
  u16* WqT = Abf;                 // 8192 elems (2 layers)
  u16* WkT = Abf + 8192;
  u16* WvT = Abf + 16384;
  u16* WoT = Abf + 24576;
  u16* W1T = Abf + 32768;         // 32768 elems
  u16* W2T = Abf + 65536;         // 32768 elems

  k_bias<<<1, 64, 0, stream>>>(emb, bias);
  k_wprep<<<384, 256, 0, stream>>>(Wq, Wk, Wv, Wo, W1, W2, WqT, WkT, WvT, WoT, W1T, W2T);
  k_conv<<<4096, 256, 0, stream>>>(x, conv_w, conv_b, hbuf);
  k_transpose<<<16384, 256, 0, stream>>>(lin_w, wt);
  for (int l = 0; l < 2; l++)
    k_layer2<<<4096, 256, 0, stream>>>(hbuf, emb, bias,
        WqT + l * 4096, WkT + l * 4096, WvT + l * 4096, WoT + l * 4096,
        W1T + l * 16384, W2T + l * 16384,
        bq + l * 64, bk + l * 64, bv + l * 64, bo + l * 64,
        ln1g + l * 64, ln1b + l * 64, ln2g + l * 64, ln2b + l * 64,
        b1 + l * 256, b2 + l * 64, res1 + l, res2 + l);
  k_packA<<<65536, 256, 0, stream>>>(hbuf, Abf);
  k_gemm<<<256, 256, 0, stream>>>(Abf, wt, lin_b, out);
}

// Round 5
// 861.141 us; speedup vs baseline: 10.1180x; 1.2721x over previous
//
#include <hip/hip_runtime.h>
#include <hip/hip_bf16.h>
#include <stdint.h>

// ---------- helpers ----------
#define AS1(p) ((const __attribute__((address_space(1))) void*)(p))
#define AS3(p) ((__attribute__((address_space(3))) void*)(p))

typedef __bf16 bf16x8 __attribute__((ext_vector_type(8)));
typedef float f32x4 __attribute__((ext_vector_type(4)));
typedef unsigned short u16;

#define MFMA(a, b, cc) __builtin_amdgcn_mfma_f32_16x16x32_bf16(a, b, cc, 0, 0, 0)
// intra-wave LDS write->read fence (rule #18 pattern): waves' DS ops execute in
// order; this stops the COMPILER from reordering across the dependency.
#define LDS_FENCE() do { asm volatile("s_waitcnt lgkmcnt(0)" ::: "memory"); \
                         __builtin_amdgcn_sched_barrier(0); } while (0)

__device__ __forceinline__ u16 f2bf(float f) {
  unsigned u = __builtin_bit_cast(unsigned, f);
  u = (u + 0x7FFFu + ((u >> 16) & 1u)) >> 16;   // RNE
  return (u16)u;
}

// ---------- constants ----------
// B=16 L=4096 N=64 D=64 H=4 WAVE=16 T=256 DFF=256 DH=16 TOPK=16

// ---------- k_bias ----------
__global__ void k_bias(const float* __restrict__ emb, float* __restrict__ bias) {
  __shared__ float e[64 * 64];
  __shared__ float nrm[64];
  __shared__ float cosr[64 * 65];
  int tid = threadIdx.x;  // 64 threads
  for (int idx = tid; idx < 4096; idx += 64) e[idx] = emb[idx];
  __syncthreads();
  float s = 0.f;
  for (int j = 0; j < 64; j++) { float v = e[tid * 64 + j]; s += v * v; }
  nrm[tid] = sqrtf(s);
  __syncthreads();
  for (int jj = 0; jj < 64; jj++) {
    float d = 0.f;
    for (int kk = 0; kk < 64; kk++) d += e[tid * 64 + kk] * e[jj * 64 + kk];
    cosr[tid * 65 + jj] = d / (nrm[tid] * nrm[jj]);
  }
  unsigned long long sel = 0ull;
  for (int it = 0; it < 16; it++) {
    float best = -1e30f; int bi = 0;
    for (int j = 0; j < 64; j++) {
      if ((sel >> j) & 1ull) continue;
      float c = cosr[tid * 65 + j];
      if (c > best) { best = c; bi = j; }
    }
    sel |= (1ull << bi);
  }
  for (int j = 0; j < 64; j++)
    bias[tid * 64 + j] = ((sel >> j) & 1ull) ? 0.0f : -1e9f;
}

// ---------- k_conv ----------
__global__ void k_conv(const float* __restrict__ x, const float* __restrict__ conv_w,
                       const float* __restrict__ conv_b, float* __restrict__ h) {
  int bt = blockIdx.x;
  int b = bt >> 8, t = bt & 255;
  __shared__ float xs[16 * 64];
  int tid = threadIdx.x;
  for (int idx = tid; idx < 1024; idx += 256)
    xs[idx] = x[((size_t)b * 4096 + t * 16 + (idx >> 6)) * 64 + (idx & 63)];
  __syncthreads();
  int d = tid & 63, n0 = (tid >> 6) << 4;
  float xv[16];
  #pragma unroll
  for (int w = 0; w < 16; w++) xv[w] = xs[w * 64 + d];
  for (int n = n0; n < n0 + 16; n++) {
    float acc = conv_b[d * 64 + n];
    const float* wp = &conv_w[(d * 64 + n) * 16];
    #pragma unroll
    for (int w = 0; w < 16; w++) acc += xv[w] * wp[w];
    h[((size_t)bt * 64 + n) * 64 + d] = acc;
  }
}

// ---------- k_wprep: transpose weights -> bf16 [n][k] ----------
__global__ void k_wprep(const float* __restrict__ Wq, const float* __restrict__ Wk,
                        const float* __restrict__ Wv, const float* __restrict__ Wo,
                        const float* __restrict__ W1, const float* __restrict__ W2,
                        u16* __restrict__ WqT, u16* __restrict__ WkT,
                        u16* __restrict__ WvT, u16* __restrict__ WoT,
                        u16* __restrict__ W1T, u16* __restrict__ W2T) {
  int e = blockIdx.x * 256 + threadIdx.x;   // 98304 total
  int l = e / 49152, r = e % 49152;
  if (r < 16384) {
    int mat = r >> 12, i = r & 4095, n = i >> 6, k = i & 63;
    const float* W = mat == 0 ? Wq : mat == 1 ? Wk : mat == 2 ? Wv : Wo;
    u16* WT = mat == 0 ? WqT : mat == 1 ? WkT : mat == 2 ? WvT : WoT;
    WT[l * 4096 + i] = f2bf(W[l * 4096 + k * 64 + n]);
  } else if (r < 32768) {
    int i = r - 16384, n = i >> 6, k = i & 63;
    W1T[l * 16384 + i] = f2bf(W1[l * 16384 + k * 256 + n]);
  } else {
    int i = r - 32768, n = i >> 8, k = i & 255;
    W2T[l * 16384 + i] = f2bf(W2[l * 16384 + k * 64 + n]);
  }
}

// ---------- k_layer2: fused MFMA transformer layer, one (b,t) per block ----------
// LDS 79872 B -> 2 blocks/CU. aout==nullptr: write h (fp32) back to hbuf;
// aout!=nullptr (last layer): write bf16 directly into GEMM A matrix (packA fused).
__global__ __launch_bounds__(256, 2) void k_layer2(
    float* __restrict__ hbuf, const float* __restrict__ emb, const float* __restrict__ bias,
    const u16* __restrict__ WqT, const u16* __restrict__ WkT,
    const u16* __restrict__ WvT, const u16* __restrict__ WoT,
    const u16* __restrict__ W1T, const u16* __restrict__ W2T,
    const float* __restrict__ bq, const float* __restrict__ bk,
    const float* __restrict__ bv, const float* __restrict__ bo,
    const float* __restrict__ ln1g, const float* __restrict__ ln1b,
    const float* __restrict__ ln2g, const float* __restrict__ ln2b,
    const float* __restrict__ b1, const float* __restrict__ b2,
    const float* __restrict__ r1p, const float* __restrict__ r2p,
    u16* __restrict__ aout) {
  __shared__ __align__(16) unsigned char smem[79872];
  float* hres = (float*)smem;
  u16* act = (u16*)(smem + 17408);
  u16* qb  = (u16*)(smem + 26624);
  u16* kb  = (u16*)(smem + 44032);
  u16* vtb = (u16*)(smem + 61440);
  u16* pb  = (u16*)(smem + 70656);
  u16* gb  = (u16*)(smem + 26624);

  const int tid = threadIdx.x;
  const int w = tid >> 6, lane = tid & 63;
  const int g = lane >> 4, c = lane & 15;
  const size_t base = (size_t)blockIdx.x << 12;
  const float r1 = *r1p, r2 = *r2p;

  // phase 1: load h, hin = h+emb -> act(bf16); zero qb/kb
  #pragma unroll
  for (int i = 0; i < 4; i++) {
    int v = tid + (i << 8);
    f32x4 hv = ((const f32x4*)(hbuf + base))[v];
    f32x4 ev = ((const f32x4*)emb)[v];
    int n = v >> 4, d = (v & 15) << 2;
    *(f32x4*)&hres[n * 68 + d] = hv;
    ushort4 u;
    u.x = f2bf(hv[0] + ev[0]); u.y = f2bf(hv[1] + ev[1]);
    u.z = f2bf(hv[2] + ev[2]); u.w = f2bf(hv[3] + ev[3]);
    *(ushort4*)&act[n * 72 + d] = u;
  }
  for (int i = tid; i < 2176; i += 256) {
    f32x4 z; z[0] = 0.f; z[1] = 0.f; z[2] = 0.f; z[3] = 0.f;
    ((f32x4*)(smem + 26624))[i] = z;
  }
  __syncthreads();   // bar1

  bf16x8 af[4][2];
  auto load_af_act = [&]() {
    #pragma unroll
    for (int rt = 0; rt < 4; rt++)
      #pragma unroll
      for (int ks = 0; ks < 2; ks++)
        af[rt][ks] = *(const bf16x8*)&act[(rt * 16 + c) * 72 + ks * 32 + g * 8];
  };
  auto gemm64 = [&](const u16* __restrict__ Wt, f32x4 acc[4]) {
    #pragma unroll
    for (int rt = 0; rt < 4; rt++) { acc[rt][0] = 0.f; acc[rt][1] = 0.f; acc[rt][2] = 0.f; acc[rt][3] = 0.f; }
    #pragma unroll
    for (int ks = 0; ks < 2; ks++) {
      bf16x8 bw = *(const bf16x8*)&Wt[(w * 16 + c) * 64 + ks * 32 + g * 8];
      #pragma unroll
      for (int rt = 0; rt < 4; rt++) acc[rt] = MFMA(af[rt][ks], bw, acc[rt]);
    }
  };

  // phase 2: QKV (col-split: wave w owns cols/head w)
  load_af_act();
  {
    f32x4 aq[4], ak[4], av[4];
    gemm64(WqT, aq); gemm64(WkT, ak); gemm64(WvT, av);
    float bqv = bq[w * 16 + c], bkv = bk[w * 16 + c], bvv = bv[w * 16 + c];
    #pragma unroll
    for (int rt = 0; rt < 4; rt++) {
      #pragma unroll
      for (int jj = 0; jj < 4; jj++) {
        int row = rt * 16 + g * 4 + jj;
        qb[row * 136 + w * 32 + c] = f2bf(aq[rt][jj] + bqv);
        kb[row * 136 + w * 32 + c] = f2bf(ak[rt][jj] + bkv);
      }
      ushort4 pv;
      pv.x = f2bf(av[rt][0] + bvv); pv.y = f2bf(av[rt][1] + bvv);
      pv.z = f2bf(av[rt][2] + bvv); pv.w = f2bf(av[rt][3] + bvv);
      *(ushort4*)&vtb[(w * 16 + c) * 72 + rt * 16 + g * 4] = pv;
    }
  }
  __syncthreads();   // bar2

  // phase 3: attention (row-split: wave w owns query rows 16w..16w+15).
  // pb stripe (rows 16w..16w+15) is written AND read only by wave w ->
  // no cross-wave hazard; intra-wave DS ordering + LDS_FENCE suffices.
  {
    float bias_r[4][4];
    #pragma unroll
    for (int jj = 0; jj < 4; jj++)
      #pragma unroll
      for (int ct = 0; ct < 4; ct++)
        bias_r[jj][ct] = bias[(w * 16 + g * 4 + jj) * 64 + ct * 16 + c];

    #pragma unroll
    for (int h = 0; h < 4; h++) {
      bf16x8 aq = *(const bf16x8*)&qb[(w * 16 + c) * 136 + h * 32 + g * 8];
      f32x4 sacc[4];
      #pragma unroll
      for (int ct = 0; ct < 4; ct++) { sacc[ct][0]=0.f; sacc[ct][1]=0.f; sacc[ct][2]=0.f; sacc[ct][3]=0.f; }
      #pragma unroll
      for (int ct = 0; ct < 4; ct++) {
        bf16x8 bk8 = *(const bf16x8*)&kb[(ct * 16 + c) * 136 + h * 32 + g * 8];
        sacc[ct] = MFMA(aq, bk8, sacc[ct]);
      }
      #pragma unroll
      for (int jj = 0; jj < 4; jj++) {
        float s0 = sacc[0][jj] * 0.25f + bias_r[jj][0];
        float s1 = sacc[1][jj] * 0.25f + bias_r[jj][1];
        float s2 = sacc[2][jj] * 0.25f + bias_r[jj][2];
        float s3 = sacc[3][jj] * 0.25f + bias_r[jj][3];
        float m = fmaxf(fmaxf(s0, s1), fmaxf(s2, s3));
        m = fmaxf(m, __shfl_xor(m, 1)); m = fmaxf(m, __shfl_xor(m, 2));
        m = fmaxf(m, __shfl_xor(m, 4)); m = fmaxf(m, __shfl_xor(m, 8));
        float e0 = __expf(s0 - m), e1 = __expf(s1 - m), e2 = __expf(s2 - m), e3 = __expf(s3 - m);
        float sum = e0 + e1 + e2 + e3;
        sum += __shfl_xor(sum, 1); sum += __shfl_xor(sum, 2);
        sum += __shfl_xor(sum, 4); sum += __shfl_xor(sum, 8);
        float inv = 1.0f / sum;
        int prow = w * 16 + g * 4 + jj;
        pb[prow * 72 +  0 + c] = f2bf(e0 * inv);
        pb[prow * 72 + 16 + c] = f2bf(e1 * inv);
        pb[prow * 72 + 32 + c] = f2bf(e2 * inv);
        pb[prow * 72 + 48 + c] = f2bf(e3 * inv);
      }
      LDS_FENCE();   // RAW: pb writes -> pb reads (intra-wave)
      f32x4 oacc; oacc[0]=0.f; oacc[1]=0.f; oacc[2]=0.f; oacc[3]=0.f;
      #pragma unroll
      for (int ks = 0; ks < 2; ks++) {
        bf16x8 ap  = *(const bf16x8*)&pb[(w * 16 + c) * 72 + ks * 32 + g * 8];
        bf16x8 bv8 = *(const bf16x8*)&vtb[(h * 16 + c) * 72 + ks * 32 + g * 8];
        oacc = MFMA(ap, bv8, oacc);
      }
      LDS_FENCE();   // WAR: pb reads -> next head's pb writes (intra-wave)
      #pragma unroll
      for (int jj = 0; jj < 4; jj++)
        act[(w * 16 + g * 4 + jj) * 72 + h * 16 + c] = f2bf(oacc[jj]);
    }
  }
  __syncthreads();   // bar3

  // phase 4: proj + residual (col-split)
  load_af_act();
  {
    f32x4 po[4];
    gemm64(WoT, po);
    float bov = bo[w * 16 + c];
    #pragma unroll
    for (int rt = 0; rt < 4; rt++)
      #pragma unroll
      for (int jj = 0; jj < 4; jj++) {
        int idx = (rt * 16 + g * 4 + jj) * 68 + w * 16 + c;
        hres[idx] += r1 * (po[rt][jj] + bov);
      }
  }
  __syncthreads();   // bar4

  // phase 5: LN1 -> act (bf16 FFN input) AND hres (fp32 residual)
  {
    int row = w * 16 + (lane >> 2), c0 = (lane & 3) << 4;
    float s = 0.f, s2 = 0.f;
    #pragma unroll
    for (int jv = 0; jv < 4; jv++) {
      f32x4 v = *(const f32x4*)&hres[row * 68 + c0 + jv * 4];
      s += v[0] + v[1] + v[2] + v[3];
      s2 += v[0]*v[0] + v[1]*v[1] + v[2]*v[2] + v[3]*v[3];
    }
    s += __shfl_xor(s, 1);  s += __shfl_xor(s, 2);
    s2 += __shfl_xor(s2, 1); s2 += __shfl_xor(s2, 2);
    float mean = s * 0.015625f, var = s2 * 0.015625f - mean * mean;
    float rstd = rsqrtf(var + 1e-5f);
    #pragma unroll
    for (int j = 0; j < 16; j++) {
      float val = (hres[row * 68 + c0 + j] - mean) * rstd * ln1g[c0 + j] + ln1b[c0 + j];
      act[row * 72 + c0 + j] = f2bf(val);
      hres[row * 68 + c0 + j] = val;
    }
  }
  __syncthreads();   // bar5

  // phase 6: FFN1 (col-split) -> gb (overlays qb/kb)
  load_af_act();
  #pragma unroll
  for (int half = 0; half < 2; half++) {
    f32x4 fa[2][4];
    #pragma unroll
    for (int ci = 0; ci < 2; ci++)
      #pragma unroll
      for (int rt = 0; rt < 4; rt++) { fa[ci][rt][0]=0.f; fa[ci][rt][1]=0.f; fa[ci][rt][2]=0.f; fa[ci][rt][3]=0.f; }
    #pragma unroll
    for (int ci = 0; ci < 2; ci++) {
      int n0 = w * 64 + half * 32 + ci * 16;
      #pragma unroll
      for (int ks = 0; ks < 2; ks++) {
        bf16x8 bw = *(const bf16x8*)&W1T[(n0 + c) * 64 + ks * 32 + g * 8];
        #pragma unroll
        for (int rt = 0; rt < 4; rt++) fa[ci][rt] = MFMA(af[rt][ks], bw, fa[ci][rt]);
      }
    }
    #pragma unroll
    for (int ci = 0; ci < 2; ci++) {
      int col = w * 64 + half * 32 + ci * 16 + c;
      float b1v = b1[col];
      #pragma unroll
      for (int rt = 0; rt < 4; rt++)
        #pragma unroll
        for (int jj = 0; jj < 4; jj++) {
          float xg = fa[ci][rt][jj] + b1v;
          float u2 = 1.5957691216057308f * (xg + 0.044715f * xg * xg * xg);
          float t = 1.f - 2.f / (1.f + __expf(u2));
          gb[(rt * 16 + g * 4 + jj) * 264 + col] = f2bf(0.5f * xg * (1.f + t));
        }
    }
  }
  __syncthreads();   // bar6

  // phase 7: FFN2 + residual (col-split)
  {
    f32x4 a2[4];
    #pragma unroll
    for (int rt = 0; rt < 4; rt++) { a2[rt][0]=0.f; a2[rt][1]=0.f; a2[rt][2]=0.f; a2[rt][3]=0.f; }
    #pragma unroll
    for (int ks = 0; ks < 8; ks++) {
      bf16x8 bw = *(const bf16x8*)&W2T[(w * 16 + c) * 256 + ks * 32 + g * 8];
      #pragma unroll
      for (int rt = 0; rt < 4; rt++) {
        bf16x8 ag = *(const bf16x8*)&gb[(rt * 16 + c) * 264 + ks * 32 + g * 8];
        a2[rt] = MFMA(ag, bw, a2[rt]);
      }
    }
    float b2v = b2[w * 16 + c];
    #pragma unroll
    for (int rt = 0; rt < 4; rt++)
      #pragma unroll
      for (int jj = 0; jj < 4; jj++) {
        int idx = (rt * 16 + g * 4 + jj) * 68 + w * 16 + c;
        hres[idx] += r2 * (a2[rt][jj] + b2v);
      }
  }
  __syncthreads();   // bar7

  // phase 8: LN2 -> hbuf (fp32) or fused packA -> aout (bf16 GEMM A)
  {
    int row = w * 16 + (lane >> 2), c0 = (lane & 3) << 4;
    float s = 0.f, s2 = 0.f;
    #pragma unroll
    for (int jv = 0; jv < 4; jv++) {
      f32x4 v = *(const f32x4*)&hres[row * 68 + c0 + jv * 4];
      s += v[0] + v[1] + v[2] + v[3];
      s2 += v[0]*v[0] + v[1]*v[1] + v[2]*v[2] + v[3]*v[3];
    }
    s += __shfl_xor(s, 1);  s += __shfl_xor(s, 2);
    s2 += __shfl_xor(s2, 1); s2 += __shfl_xor(s2, 2);
    float mean = s * 0.015625f, var = s2 * 0.015625f - mean * mean;
    float rstd = rsqrtf(var + 1e-5f);
    if (aout) {
      int b = (int)(blockIdx.x >> 8), t = (int)(blockIdx.x & 255);
      u16* ao = aout + (((size_t)(b * 64 + row)) << 14) + (t << 6) + c0;
      #pragma unroll
      for (int jv = 0; jv < 4; jv++) {
        f32x4 v = *(const f32x4*)&hres[row * 68 + c0 + jv * 4];
        ushort4 us;
        #pragma unroll
        for (int e = 0; e < 4; e++) {
          float o = (v[e] - mean) * rstd * ln2g[c0 + jv * 4 + e] + ln2b[c0 + jv * 4 + e];
          ((u16*)&us)[e] = f2bf(o);
        }
        *(ushort4*)&ao[jv * 4] = us;
      }
    } else {
      #pragma unroll
      for (int jv = 0; jv < 4; jv++) {
        f32x4 v = *(const f32x4*)&hres[row * 68 + c0 + jv * 4];
        f32x4 o;
        #pragma unroll
        for (int e = 0; e < 4; e++)
          o[e] = (v[e] - mean) * rstd * ln2g[c0 + jv * 4 + e] + ln2b[c0 + jv * 4 + e];
        *(f32x4*)&hbuf[base + row * 64 + c0 + jv * 4] = o;
      }
    }
  }
}

// ---------- k_transpose: lin_w [16384][4096] f32 -> wt [4096][16384] bf16 ----------
__global__ void k_transpose(const float* __restrict__ w, u16* __restrict__ wt) {
  __shared__ float tile[64][65];
  int bk = blockIdx.x & 255;
  int bn = blockIdx.x >> 8;
  int tid = threadIdx.x;
  int c = tid & 63, r0 = tid >> 6;
  #pragma unroll
  for (int i = 0; i < 16; i++) {
    int r = r0 + i * 4;
    tile[r][c] = w[((size_t)(bk * 64 + r)) * 4096 + bn * 64 + c];
  }
  __syncthreads();
  #pragma unroll
  for (int i = 0; i < 16; i++) {
    int r = r0 + i * 4;
    wt[((size_t)(bn * 64 + r)) * 16384 + bk * 64 + c] = f2bf(tile[c][r]);
  }
}

// ---------- k_gemm2: K-split x4, 1024 blocks, XOR-swizzled LDS ----------
// P[split][1024][4096] fp32 partials; logical colchunk lc <-> physical pc = lc ^ (row&7)
__global__ __launch_bounds__(256, 4) void k_gemm2(const u16* __restrict__ A,
                                                  const u16* __restrict__ Bt,
                                                  float* __restrict__ P) {
  __shared__ u16 As[128 * 64];
  __shared__ u16 Bs[128 * 64];
  const int tid = threadIdx.x;
  const int lane = tid & 63;
  const int wv = tid >> 6;
  const int split = blockIdx.x >> 8;
  const int tile = blockIdx.x & 255;
  const int bm = tile >> 5, bn = tile & 31;
  const int m0 = bm << 7, n0 = bn << 7;
  f32x4 acc[4][4];
  #pragma unroll
  for (int i = 0; i < 4; i++)
    #pragma unroll
    for (int j = 0; j < 4; j++) { acc[i][j][0]=0.f; acc[i][j][1]=0.f; acc[i][j][2]=0.f; acc[i][j][3]=0.f; }

  const int r15 = lane & 15;
  const int g = lane >> 4;
  const int wm = wv >> 1, wn = wv & 1;
  const u16* abase = A  + ((size_t)m0 << 14) + (split << 12);
  const u16* bbase = Bt + ((size_t)n0 << 14) + (split << 12);

  for (int kt = 0; kt < 64; kt++) {
    const u16* ab = abase + (kt << 6);
    const u16* bb = bbase + (kt << 6);
    #pragma unroll
    for (int j = 0; j < 4; j++) {
      int cix = ((wv * 4 + j) << 6) + lane;      // physical 16B chunk 0..1023
      int row = cix >> 3;
      int sc  = (cix & 7) ^ (row & 7);           // swizzled source colchunk
      int off = (row << 14) + (sc << 3);
      __builtin_amdgcn_global_load_lds(AS1(ab + off), AS3(&As[(wv * 4 + j) << 9]), 16, 0, 0);
      __builtin_amdgcn_global_load_lds(AS1(bb + off), AS3(&Bs[(wv * 4 + j) << 9]), 16, 0, 0);
    }
    __syncthreads();
    #pragma unroll
    for (int ks = 0; ks < 2; ks++) {
      const int pc = ((ks << 2) + g) ^ (r15 & 7);  // swizzled read colchunk
      bf16x8 af2[4], bfr[4];
      #pragma unroll
      for (int mi = 0; mi < 4; mi++)
        af2[mi] = *(const bf16x8*)&As[((wm << 6) + mi * 16 + r15) * 64 + (pc << 3)];
      #pragma unroll
      for (int ni = 0; ni < 4; ni++)
        bfr[ni] = *(const bf16x8*)&Bs[((wn << 6) + ni * 16 + r15) * 64 + (pc << 3)];
      #pragma unroll
      for (int mi = 0; mi < 4; mi++)
        #pragma unroll
        for (int ni = 0; ni < 4; ni++)
          acc[mi][ni] = MFMA(af2[mi], bfr[ni], acc[mi][ni]);
    }
    __syncthreads();
  }

  float* Pp = P + ((size_t)split << 22);
  #pragma unroll
  for (int mi = 0; mi < 4; mi++) {
    #pragma unroll
    for (int ni = 0; ni < 4; ni++) {
      int col = n0 + (wn << 6) + ni * 16 + r15;
      #pragma unroll
      for (int j = 0; j < 4; j++) {
        int row = m0 + (wm << 6) + mi * 16 + (g << 2) + j;
        Pp[((size_t)row << 12) + col] = acc[mi][ni][j];
      }
    }
  }
}

// ---------- k_reduce: sum 4 K-splits + bias, transpose to out[b,l,n] ----------
__global__ void k_reduce(const float* __restrict__ P, const float* __restrict__ lin_b,
                         float* __restrict__ out) {
  __shared__ float tile[64][65];
  int b = blockIdx.x >> 6, lt = blockIdx.x & 63;
  int tid = threadIdx.x, c = tid & 63, r0 = tid >> 6;
  const float* Pb = P + (((size_t)b * 64) << 12) + (lt << 6);
  #pragma unroll
  for (int i = 0; i < 16; i++) {
    int node = r0 + i * 4;
    size_t off = ((size_t)node << 12) + c;
    float s = Pb[off] + Pb[off + 4194304] + Pb[off + 8388608] + Pb[off + 12582912];
    tile[node][c] = s;
  }
  __syncthreads();
  #pragma unroll
  for (int i = 0; i < 16; i++) {
    int lo = r0 + i * 4;
    out[((size_t)(b * 4096 + lt * 64 + lo)) * 64 + c] = tile[c][lo] + lin_b[lt * 64 + lo];
  }
}

// ---------- launch ----------
extern "C" void kernel_launch(void* const* d_in, const int* in_sizes, int n_in,
                              void* d_out, int out_size, void* d_ws, size_t ws_size,
                              hipStream_t stream) {
  const float* x      = (const float*)d_in[0];
  const float* emb    = (const float*)d_in[1];
  const float* conv_w = (const float*)d_in[2];
  const float* conv_b = (const float*)d_in[3];
  const float* Wq = (const float*)d_in[4],  *bq = (const float*)d_in[5];
  const float* Wk = (const float*)d_in[6],  *bk = (const float*)d_in[7];
  const float* Wv = (const float*)d_in[8],  *bv = (const float*)d_in[9];
  const float* Wo = (const float*)d_in[10], *bo = (const float*)d_in[11];
  const float* ln1g = (const float*)d_in[12], *ln1b = (const float*)d_in[13];
  const float* ln2g = (const float*)d_in[14], *ln2b = (const float*)d_in[15];
  const float* W1 = (const float*)d_in[16], *b1 = (const float*)d_in[17];
  const float* W2 = (const float*)d_in[18], *b2 = (const float*)d_in[19];
  const float* res1 = (const float*)d_in[20], *res2 = (const float*)d_in[21];
  const float* lin_w = (const float*)d_in[22], *lin_b = (const float*)d_in[23];
  float* out = (float*)d_out;

  char* ws = (char*)d_ws;
  float* bias   = (float*)ws;                                        //    16,384 B
  float* hbuf   = (float*)(ws + 16384);                              // 67,108,864 B (layers)
  float* Ppart  = hbuf;                                              // overlay: GEMM partials (after layers)
  u16*   wt     = (u16*)(ws + 16384 + 67108864);                     // 134,217,728 B
  u16*   Abf    = (u16*)(ws + 16384 + 67108864 + 134217728);         // 33,554,432 B
  u16*   WTb    = (u16*)(ws + 16384 + 67108864 + 134217728 + 33554432); // 196,608 B
  // total ws use: 235,094,016 B
  u16* WqT = WTb;                 // 8192 elems (2 layers)
  u16* WkT = WTb + 8192;
  u16* WvT = WTb + 16384;
  u16* WoT = WTb + 24576;
  u16* W1T = WTb + 32768;         // 32768 elems
  u16* W2T = WTb + 65536;         // 32768 elems

  k_bias<<<1, 64, 0, stream>>>(emb, bias);
  k_wprep<<<384, 256, 0, stream>>>(Wq, Wk, Wv, Wo, W1, W2, WqT, WkT, WvT, WoT, W1T, W2T);
  k_conv<<<4096, 256, 0, stream>>>(x, conv_w, conv_b, hbuf);
  k_transpose<<<16384, 256, 0, stream>>>(lin_w, wt);
  for (int l = 0; l < 2; l++)
    k_layer2<<<4096, 256, 0, stream>>>(hbuf, emb, bias,
        WqT + l * 4096, WkT + l * 4096, WvT + l * 4096, WoT + l * 4096,
        W1T + l * 16384, W2T + l * 16384,
        bq + l * 64, bk + l * 64, bv + l * 64, bo + l * 64,
        ln1g + l * 64, ln1b + l * 64, ln2g + l * 64, ln2b + l * 64,
        b1 + l * 256, b2 + l * 64, res1 + l, res2 + l,
        (l == 1) ? Abf : (u16*)nullptr);
  k_gemm2<<<1024, 256, 0, stream>>>(Abf, wt, Ppart);
  k_reduce<<<1024, 256, 0, stream>>>(Ppart, lin_b, out);
}

// Round 7
// 798.916 us; speedup vs baseline: 10.9061x; 1.0779x over previous
//
#include <hip/hip_runtime.h>
#include <hip/hip_bf16.h>
#include <stdint.h>

// ---------- helpers ----------
#define AS1(p) ((const __attribute__((address_space(1))) void*)(p))
#define AS3(p) ((__attribute__((address_space(3))) void*)(p))

typedef __bf16 bf16x8 __attribute__((ext_vector_type(8)));
typedef __bf16 bf16x4 __attribute__((ext_vector_type(4)));
typedef float f32x4 __attribute__((ext_vector_type(4)));
typedef unsigned short u16;

#define MFMA(a, b, cc) __builtin_amdgcn_mfma_f32_16x16x32_bf16(a, b, cc, 0, 0, 0)

__device__ __forceinline__ u16 f2bf(float f) {
  unsigned u = __builtin_bit_cast(unsigned, f);
  u = (u + 0x7FFFu + ((u >> 16) & 1u)) >> 16;   // RNE
  return (u16)u;
}

// ---------- constants ----------
// B=16 L=4096 N=64 D=64 H=4 WAVE=16 T=256 DFF=256 DH=16 TOPK=16

// ---------- k_bias ----------
__global__ void k_bias(const float* __restrict__ emb, float* __restrict__ bias) {
  __shared__ float e[64 * 64];
  __shared__ float nrm[64];
  __shared__ float cosr[64 * 65];
  int tid = threadIdx.x;  // 64 threads
  for (int idx = tid; idx < 4096; idx += 64) e[idx] = emb[idx];
  __syncthreads();
  float s = 0.f;
  for (int j = 0; j < 64; j++) { float v = e[tid * 64 + j]; s += v * v; }
  nrm[tid] = sqrtf(s);
  __syncthreads();
  for (int jj = 0; jj < 64; jj++) {
    float d = 0.f;
    for (int kk = 0; kk < 64; kk++) d += e[tid * 64 + kk] * e[jj * 64 + kk];
    cosr[tid * 65 + jj] = d / (nrm[tid] * nrm[jj]);
  }
  unsigned long long sel = 0ull;
  for (int it = 0; it < 16; it++) {
    float best = -1e30f; int bi = 0;
    for (int j = 0; j < 64; j++) {
      if ((sel >> j) & 1ull) continue;
      float c = cosr[tid * 65 + j];
      if (c > best) { best = c; bi = j; }
    }
    sel |= (1ull << bi);
  }
  for (int j = 0; j < 64; j++)
    bias[tid * 64 + j] = ((sel >> j) & 1ull) ? 0.0f : -1e9f;
}

// ---------- k_conv ----------
__global__ void k_conv(const float* __restrict__ x, const float* __restrict__ conv_w,
                       const float* __restrict__ conv_b, float* __restrict__ h) {
  int bt = blockIdx.x;
  int b = bt >> 8, t = bt & 255;
  __shared__ float xs[16 * 64];
  int tid = threadIdx.x;
  for (int idx = tid; idx < 1024; idx += 256)
    xs[idx] = x[((size_t)b * 4096 + t * 16 + (idx >> 6)) * 64 + (idx & 63)];
  __syncthreads();
  int d = tid & 63, n0 = (tid >> 6) << 4;
  float xv[16];
  #pragma unroll
  for (int w = 0; w < 16; w++) xv[w] = xs[w * 64 + d];
  for (int n = n0; n < n0 + 16; n++) {
    float acc = conv_b[d * 64 + n];
    const float* wp = &conv_w[(d * 64 + n) * 16];
    #pragma unroll
    for (int w = 0; w < 16; w++) acc += xv[w] * wp[w];
    h[((size_t)bt * 64 + n) * 64 + d] = acc;
  }
}

// ---------- k_wprep: transpose weights -> bf16 [n][k] ----------
__global__ void k_wprep(const float* __restrict__ Wq, const float* __restrict__ Wk,
                        const float* __restrict__ Wv, const float* __restrict__ Wo,
                        const float* __restrict__ W1, const float* __restrict__ W2,
                        u16* __restrict__ WqT, u16* __restrict__ WkT,
                        u16* __restrict__ WvT, u16* __restrict__ WoT,
                        u16* __restrict__ W1T, u16* __restrict__ W2T) {
  int e = blockIdx.x * 256 + threadIdx.x;   // 98304 total
  int l = e / 49152, r = e % 49152;
  if (r < 16384) {
    int mat = r >> 12, i = r & 4095, n = i >> 6, k = i & 63;
    const float* W = mat == 0 ? Wq : mat == 1 ? Wk : mat == 2 ? Wv : Wo;
    u16* WT = mat == 0 ? WqT : mat == 1 ? WkT : mat == 2 ? WvT : WoT;
    WT[l * 4096 + i] = f2bf(W[l * 4096 + k * 64 + n]);
  } else if (r < 32768) {
    int i = r - 16384, n = i >> 6, k = i & 63;
    W1T[l * 16384 + i] = f2bf(W1[l * 16384 + k * 256 + n]);
  } else {
    int i = r - 32768, n = i >> 8, k = i & 255;
    W2T[l * 16384 + i] = f2bf(W2[l * 16384 + k * 64 + n]);
  }
}

// ---------- k_layer2: fused MFMA transformer layer, one (b,t) per block ----------
// Operand-swapped weight GEMMs -> packed bf16x4/f32x4 stores. Attention phase:
// all-heads QK^T in registers -> BARRIER -> softmax writes P into dead qb/kb
// region -> BARRIER -> all-heads PV (race-free: real barriers fence the LDS
// region reuse; r6's intra-wave LDS_FENCE was nondeterministic under replay).
// LDS 79872 B -> 2 blocks/CU.
__global__ __launch_bounds__(256, 2) void k_layer2(
    float* __restrict__ hbuf, const float* __restrict__ emb, const float* __restrict__ bias,
    const u16* __restrict__ WqT, const u16* __restrict__ WkT,
    const u16* __restrict__ WvT, const u16* __restrict__ WoT,
    const u16* __restrict__ W1T, const u16* __restrict__ W2T,
    const float* __restrict__ bq, const float* __restrict__ bk,
    const float* __restrict__ bv, const float* __restrict__ bo,
    const float* __restrict__ ln1g, const float* __restrict__ ln1b,
    const float* __restrict__ ln2g, const float* __restrict__ ln2b,
    const float* __restrict__ b1, const float* __restrict__ b2,
    const float* __restrict__ r1p, const float* __restrict__ r2p,
    u16* __restrict__ aout) {
  __shared__ __align__(16) unsigned char smem[79872];
  float* hres = (float*)smem;                 // [64][68] f32
  __bf16* act = (__bf16*)(smem + 17408);      // [64][72]
  __bf16* qb  = (__bf16*)(smem + 26624);      // [64][136] (per-head 32-wide, hi 16 zero)
  __bf16* kb  = (__bf16*)(smem + 44032);      // [64][136]
  __bf16* vtb = (__bf16*)(smem + 61440);      // [64][72]  V^T [d][node]
  __bf16* ps  = (__bf16*)(smem + 26624);      // [64][264] P[q][h*64+key], overlays qb+kb (dead)
  __bf16* gb  = (__bf16*)(smem + 26624);      // [64][264] FFN hidden, overlays qb+kb

  const int tid = threadIdx.x;
  const int w = tid >> 6, lane = tid & 63;
  const int g = lane >> 4, c = lane & 15;
  const size_t base = (size_t)blockIdx.x << 12;
  const float r1 = *r1p, r2 = *r2p;

  // phase 1: load h, hin = h+emb -> act(bf16); zero qb/kb (padding lanes)
  #pragma unroll
  for (int i = 0; i < 4; i++) {
    int v = tid + (i << 8);
    f32x4 hv = ((const f32x4*)(hbuf + base))[v];
    f32x4 ev = ((const f32x4*)emb)[v];
    int n = v >> 4, d = (v & 15) << 2;
    *(f32x4*)&hres[n * 68 + d] = hv;
    bf16x4 u;
    u[0] = (__bf16)(hv[0] + ev[0]); u[1] = (__bf16)(hv[1] + ev[1]);
    u[2] = (__bf16)(hv[2] + ev[2]); u[3] = (__bf16)(hv[3] + ev[3]);
    *(bf16x4*)&act[n * 72 + d] = u;
  }
  for (int i = tid; i < 2176; i += 256) {
    f32x4 z; z[0] = 0.f; z[1] = 0.f; z[2] = 0.f; z[3] = 0.f;
    ((f32x4*)(smem + 26624))[i] = z;
  }
  __syncthreads();   // bar1

  bf16x8 af[4][2];
  auto load_af_act = [&]() {
    #pragma unroll
    for (int rt = 0; rt < 4; rt++)
      #pragma unroll
      for (int ks = 0; ks < 2; ks++)
        af[rt][ks] = *(const bf16x8*)&act[(rt * 16 + c) * 72 + ks * 32 + g * 8];
  };

  // phase 2: QKV. q/k operand-swapped (D[d][n]) -> packed stores into qb/kb[n][d];
  // v unswapped (D[n][d]) -> packed stores into vtb[d][n].
  load_af_act();
  {
    {  // q
      bf16x8 a0 = *(const bf16x8*)&WqT[(w * 16 + c) * 64 + g * 8];
      bf16x8 a1 = *(const bf16x8*)&WqT[(w * 16 + c) * 64 + 32 + g * 8];
      float b4[4];
      #pragma unroll
      for (int jj = 0; jj < 4; jj++) b4[jj] = bq[w * 16 + g * 4 + jj];
      #pragma unroll
      for (int nt = 0; nt < 4; nt++) {
        f32x4 a; a[0]=0.f; a[1]=0.f; a[2]=0.f; a[3]=0.f;
        a = MFMA(a0, af[nt][0], a);
        a = MFMA(a1, af[nt][1], a);
        bf16x4 st;
        #pragma unroll
        for (int jj = 0; jj < 4; jj++) st[jj] = (__bf16)(a[jj] + b4[jj]);
        *(bf16x4*)&qb[(nt * 16 + c) * 136 + w * 32 + g * 4] = st;
      }
    }
    {  // k
      bf16x8 a0 = *(const bf16x8*)&WkT[(w * 16 + c) * 64 + g * 8];
      bf16x8 a1 = *(const bf16x8*)&WkT[(w * 16 + c) * 64 + 32 + g * 8];
      float b4[4];
      #pragma unroll
      for (int jj = 0; jj < 4; jj++) b4[jj] = bk[w * 16 + g * 4 + jj];
      #pragma unroll
      for (int nt = 0; nt < 4; nt++) {
        f32x4 a; a[0]=0.f; a[1]=0.f; a[2]=0.f; a[3]=0.f;
        a = MFMA(a0, af[nt][0], a);
        a = MFMA(a1, af[nt][1], a);
        bf16x4 st;
        #pragma unroll
        for (int jj = 0; jj < 4; jj++) st[jj] = (__bf16)(a[jj] + b4[jj]);
        *(bf16x4*)&kb[(nt * 16 + c) * 136 + w * 32 + g * 4] = st;
      }
    }
    {  // v (unswapped: D[n][d], pack along n into vtb[d][n])
      bf16x8 b0 = *(const bf16x8*)&WvT[(w * 16 + c) * 64 + g * 8];
      bf16x8 b1v_ = *(const bf16x8*)&WvT[(w * 16 + c) * 64 + 32 + g * 8];
      float bvv = bv[w * 16 + c];
      #pragma unroll
      for (int nt = 0; nt < 4; nt++) {
        f32x4 a; a[0]=0.f; a[1]=0.f; a[2]=0.f; a[3]=0.f;
        a = MFMA(af[nt][0], b0, a);
        a = MFMA(af[nt][1], b1v_, a);
        bf16x4 st;
        #pragma unroll
        for (int jj = 0; jj < 4; jj++) st[jj] = (__bf16)(a[jj] + bvv);
        *(bf16x4*)&vtb[(w * 16 + c) * 72 + nt * 16 + g * 4] = st;
      }
    }
  }
  __syncthreads();   // bar2

  // phase 3: attention (row-split: wave w owns query rows 16w..16w+15)
  {
    // Stage A: all 4 heads' QK^T into registers (static indexing, full unroll)
    float bias_r[4][4];
    #pragma unroll
    for (int jj = 0; jj < 4; jj++)
      #pragma unroll
      for (int ct = 0; ct < 4; ct++)
        bias_r[jj][ct] = bias[(w * 16 + g * 4 + jj) * 64 + ct * 16 + c];

    f32x4 sc4[4][4];   // [head][ct]
    #pragma unroll
    for (int h = 0; h < 4; h++) {
      bf16x8 aq = *(const bf16x8*)&qb[(w * 16 + c) * 136 + h * 32 + g * 8];
      #pragma unroll
      for (int ct = 0; ct < 4; ct++) {
        bf16x8 bk8 = *(const bf16x8*)&kb[(ct * 16 + c) * 136 + h * 32 + g * 8];
        f32x4 z0; z0[0]=0.f; z0[1]=0.f; z0[2]=0.f; z0[3]=0.f;
        sc4[h][ct] = MFMA(aq, bk8, z0);
      }
    }
    __syncthreads();   // all waves done reading qb/kb; region becomes P

    // Stage B: softmax (registers + 16-lane-group shfl) -> P into ps
    #pragma unroll
    for (int h = 0; h < 4; h++) {
      #pragma unroll
      for (int jj = 0; jj < 4; jj++) {
        float s0 = sc4[h][0][jj] * 0.25f + bias_r[jj][0];
        float s1 = sc4[h][1][jj] * 0.25f + bias_r[jj][1];
        float s2 = sc4[h][2][jj] * 0.25f + bias_r[jj][2];
        float s3 = sc4[h][3][jj] * 0.25f + bias_r[jj][3];
        float m = fmaxf(fmaxf(s0, s1), fmaxf(s2, s3));
        m = fmaxf(m, __shfl_xor(m, 1)); m = fmaxf(m, __shfl_xor(m, 2));
        m = fmaxf(m, __shfl_xor(m, 4)); m = fmaxf(m, __shfl_xor(m, 8));
        float e0 = __expf(s0 - m), e1 = __expf(s1 - m), e2 = __expf(s2 - m), e3 = __expf(s3 - m);
        float sum = e0 + e1 + e2 + e3;
        sum += __shfl_xor(sum, 1); sum += __shfl_xor(sum, 2);
        sum += __shfl_xor(sum, 4); sum += __shfl_xor(sum, 8);
        float inv = __builtin_amdgcn_rcpf(sum);
        int prow = w * 16 + g * 4 + jj;
        ps[prow * 264 + h * 64 +  0 + c] = (__bf16)(e0 * inv);
        ps[prow * 264 + h * 64 + 16 + c] = (__bf16)(e1 * inv);
        ps[prow * 264 + h * 64 + 32 + c] = (__bf16)(e2 * inv);
        ps[prow * 264 + h * 64 + 48 + c] = (__bf16)(e3 * inv);
      }
    }
    __syncthreads();   // P visible

    // Stage C: PV operand-swapped (D[dh][q]) -> packed bf16x4 act stores
    #pragma unroll
    for (int h = 0; h < 4; h++) {
      f32x4 oacc; oacc[0]=0.f; oacc[1]=0.f; oacc[2]=0.f; oacc[3]=0.f;
      #pragma unroll
      for (int ks = 0; ks < 2; ks++) {
        bf16x8 ap  = *(const bf16x8*)&ps[(w * 16 + c) * 264 + h * 64 + ks * 32 + g * 8];
        bf16x8 bv8 = *(const bf16x8*)&vtb[(h * 16 + c) * 72 + ks * 32 + g * 8];
        oacc = MFMA(bv8, ap, oacc);   // A=V^T[dh][key], B=P^T[key][q]
      }
      bf16x4 st;
      #pragma unroll
      for (int jj = 0; jj < 4; jj++) st[jj] = (__bf16)oacc[jj];
      *(bf16x4*)&act[(w * 16 + c) * 72 + h * 16 + g * 4] = st;
    }
  }
  __syncthreads();   // bar3

  // phase 4: proj + residual (operand-swapped: D[d][n] -> f32x4 RMW on hres)
  load_af_act();
  {
    bf16x8 a0 = *(const bf16x8*)&WoT[(w * 16 + c) * 64 + g * 8];
    bf16x8 a1 = *(const bf16x8*)&WoT[(w * 16 + c) * 64 + 32 + g * 8];
    float b4[4];
    #pragma unroll
    for (int jj = 0; jj < 4; jj++) b4[jj] = bo[w * 16 + g * 4 + jj];
    #pragma unroll
    for (int nt = 0; nt < 4; nt++) {
      f32x4 a; a[0]=0.f; a[1]=0.f; a[2]=0.f; a[3]=0.f;
      a = MFMA(a0, af[nt][0], a);
      a = MFMA(a1, af[nt][1], a);
      float* hp = &hres[(nt * 16 + c) * 68 + w * 16 + g * 4];
      f32x4 hv = *(f32x4*)hp;
      #pragma unroll
      for (int jj = 0; jj < 4; jj++) hv[jj] += r1 * (a[jj] + b4[jj]);
      *(f32x4*)hp = hv;
    }
  }
  __syncthreads();   // bar4

  // phase 5: LN1 -> act (bf16 FFN input) AND hres (fp32 residual)
  {
    int row = w * 16 + (lane >> 2), c0 = (lane & 3) << 4;
    float s = 0.f, s2 = 0.f;
    #pragma unroll
    for (int jv = 0; jv < 4; jv++) {
      f32x4 v = *(const f32x4*)&hres[row * 68 + c0 + jv * 4];
      s += v[0] + v[1] + v[2] + v[3];
      s2 += v[0]*v[0] + v[1]*v[1] + v[2]*v[2] + v[3]*v[3];
    }
    s += __shfl_xor(s, 1);  s += __shfl_xor(s, 2);
    s2 += __shfl_xor(s2, 1); s2 += __shfl_xor(s2, 2);
    float mean = s * 0.015625f, var = s2 * 0.015625f - mean * mean;
    float rstd = rsqrtf(var + 1e-5f);
    #pragma unroll
    for (int jv = 0; jv < 4; jv++) {
      f32x4 v = *(const f32x4*)&hres[row * 68 + c0 + jv * 4];
      f32x4 o; bf16x4 ob;
      #pragma unroll
      for (int e = 0; e < 4; e++) {
        o[e] = (v[e] - mean) * rstd * ln1g[c0 + jv * 4 + e] + ln1b[c0 + jv * 4 + e];
        ob[e] = (__bf16)o[e];
      }
      *(f32x4*)&hres[row * 68 + c0 + jv * 4] = o;
      *(bf16x4*)&act[row * 72 + c0 + jv * 4] = ob;
    }
  }
  __syncthreads();   // bar5

  // phase 6: FFN1 operand-swapped (D[ff][n]); wave w owns ff rows 64w..64w+63.
  // gelu via x - x*rcp(1+e). Packed bf16x4 stores into gb[n][ff].
  load_af_act();
  #pragma unroll
  for (int ft = 0; ft < 4; ft++) {
    int ffb = (w << 6) + (ft << 4);
    bf16x8 a0 = *(const bf16x8*)&W1T[(ffb + c) * 64 + g * 8];
    bf16x8 a1 = *(const bf16x8*)&W1T[(ffb + c) * 64 + 32 + g * 8];
    float b14[4];
    #pragma unroll
    for (int jj = 0; jj < 4; jj++) b14[jj] = b1[ffb + g * 4 + jj];
    #pragma unroll
    for (int nt = 0; nt < 4; nt++) {
      f32x4 a; a[0]=0.f; a[1]=0.f; a[2]=0.f; a[3]=0.f;
      a = MFMA(a0, af[nt][0], a);
      a = MFMA(a1, af[nt][1], a);
      bf16x4 st;
      #pragma unroll
      for (int jj = 0; jj < 4; jj++) {
        float xg = a[jj] + b14[jj];
        float e = __expf(1.5957691216057308f * (xg + 0.044715f * xg * xg * xg));
        float r = __builtin_amdgcn_rcpf(1.f + e);
        st[jj] = (__bf16)(xg - xg * r);
      }
      *(bf16x4*)&gb[(nt * 16 + c) * 264 + ffb + g * 4] = st;
    }
  }
  __syncthreads();   // bar6

  // phase 7: FFN2 + residual (operand-swapped: D[d][n] -> f32x4 RMW on hres)
  {
    f32x4 a2[4];
    #pragma unroll
    for (int nt = 0; nt < 4; nt++) { a2[nt][0]=0.f; a2[nt][1]=0.f; a2[nt][2]=0.f; a2[nt][3]=0.f; }
    #pragma unroll
    for (int ks = 0; ks < 8; ks++) {
      bf16x8 bw = *(const bf16x8*)&W2T[(w * 16 + c) * 256 + ks * 32 + g * 8];
      #pragma unroll
      for (int nt = 0; nt < 4; nt++) {
        bf16x8 ag = *(const bf16x8*)&gb[(nt * 16 + c) * 264 + ks * 32 + g * 8];
        a2[nt] = MFMA(bw, ag, a2[nt]);
      }
    }
    float b24[4];
    #pragma unroll
    for (int jj = 0; jj < 4; jj++) b24[jj] = b2[w * 16 + g * 4 + jj];
    #pragma unroll
    for (int nt = 0; nt < 4; nt++) {
      float* hp = &hres[(nt * 16 + c) * 68 + w * 16 + g * 4];
      f32x4 hv = *(f32x4*)hp;
      #pragma unroll
      for (int jj = 0; jj < 4; jj++) hv[jj] += r2 * (a2[nt][jj] + b24[jj]);
      *(f32x4*)hp = hv;
    }
  }
  __syncthreads();   // bar7

  // phase 8: LN2 -> hbuf (fp32) or fused packA -> aout (bf16 GEMM A)
  {
    int row = w * 16 + (lane >> 2), c0 = (lane & 3) << 4;
    float s = 0.f, s2 = 0.f;
    #pragma unroll
    for (int jv = 0; jv < 4; jv++) {
      f32x4 v = *(const f32x4*)&hres[row * 68 + c0 + jv * 4];
      s += v[0] + v[1] + v[2] + v[3];
      s2 += v[0]*v[0] + v[1]*v[1] + v[2]*v[2] + v[3]*v[3];
    }
    s += __shfl_xor(s, 1);  s += __shfl_xor(s, 2);
    s2 += __shfl_xor(s2, 1); s2 += __shfl_xor(s2, 2);
    float mean = s * 0.015625f, var = s2 * 0.015625f - mean * mean;
    float rstd = rsqrtf(var + 1e-5f);
    if (aout) {
      int b = (int)(blockIdx.x >> 8), t = (int)(blockIdx.x & 255);
      __bf16* ao = (__bf16*)aout + (((size_t)(b * 64 + row)) << 14) + (t << 6) + c0;
      #pragma unroll
      for (int jv = 0; jv < 4; jv++) {
        f32x4 v = *(const f32x4*)&hres[row * 68 + c0 + jv * 4];
        bf16x4 us;
        #pragma unroll
        for (int e = 0; e < 4; e++) {
          float o = (v[e] - mean) * rstd * ln2g[c0 + jv * 4 + e] + ln2b[c0 + jv * 4 + e];
          us[e] = (__bf16)o;
        }
        *(bf16x4*)&ao[jv * 4] = us;
      }
    } else {
      #pragma unroll
      for (int jv = 0; jv < 4; jv++) {
        f32x4 v = *(const f32x4*)&hres[row * 68 + c0 + jv * 4];
        f32x4 o;
        #pragma unroll
        for (int e = 0; e < 4; e++)
          o[e] = (v[e] - mean) * rstd * ln2g[c0 + jv * 4 + e] + ln2b[c0 + jv * 4 + e];
        *(f32x4*)&hbuf[base + row * 64 + c0 + jv * 4] = o;
      }
    }
  }
}

// ---------- k_transpose: lin_w [16384][4096] f32 -> wt [4096][16384] bf16 ----------
__global__ void k_transpose(const float* __restrict__ w, u16* __restrict__ wt) {
  __shared__ float tile[64][65];
  int bk = blockIdx.x & 255;
  int bn = blockIdx.x >> 8;
  int tid = threadIdx.x;
  int c = tid & 63, r0 = tid >> 6;
  #pragma unroll
  for (int i = 0; i < 16; i++) {
    int r = r0 + i * 4;
    tile[r][c] = w[((size_t)(bk * 64 + r)) * 4096 + bn * 64 + c];
  }
  __syncthreads();
  #pragma unroll
  for (int i = 0; i < 16; i++) {
    int r = r0 + i * 4;
    wt[((size_t)(bn * 64 + r)) * 16384 + bk * 64 + c] = f2bf(tile[c][r]);
  }
}

// ---------- k_gemm2: K-split x4, 1024 blocks, XOR-swizzled LDS ----------
__global__ __launch_bounds__(256, 4) void k_gemm2(const u16* __restrict__ A,
                                                  const u16* __restrict__ Bt,
                                                  float* __restrict__ P) {
  __shared__ u16 As[128 * 64];
  __shared__ u16 Bs[128 * 64];
  const int tid = threadIdx.x;
  const int lane = tid & 63;
  const int wv = tid >> 6;
  const int split = blockIdx.x >> 8;
  const int tile = blockIdx.x & 255;
  const int bm = tile >> 5, bn = tile & 31;
  const int m0 = bm << 7, n0 = bn << 7;
  f32x4 acc[4][4];
  #pragma unroll
  for (int i = 0; i < 4; i++)
    #pragma unroll
    for (int j = 0; j < 4; j++) { acc[i][j][0]=0.f; acc[i][j][1]=0.f; acc[i][j][2]=0.f; acc[i][j][3]=0.f; }

  const int r15 = lane & 15;
  const int g = lane >> 4;
  const int wm = wv >> 1, wn = wv & 1;
  const u16* abase = A  + ((size_t)m0 << 14) + (split << 12);
  const u16* bbase = Bt + ((size_t)n0 << 14) + (split << 12);

  for (int kt = 0; kt < 64; kt++) {
    const u16* ab = abase + (kt << 6);
    const u16* bb = bbase + (kt << 6);
    #pragma unroll
    for (int j = 0; j < 4; j++) {
      int cix = ((wv * 4 + j) << 6) + lane;
      int row = cix >> 3;
      int sc  = (cix & 7) ^ (row & 7);
      int off = (row << 14) + (sc << 3);
      __builtin_amdgcn_global_load_lds(AS1(ab + off), AS3(&As[(wv * 4 + j) << 9]), 16, 0, 0);
      __builtin_amdgcn_global_load_lds(AS1(bb + off), AS3(&Bs[(wv * 4 + j) << 9]), 16, 0, 0);
    }
    __syncthreads();
    #pragma unroll
    for (int ks = 0; ks < 2; ks++) {
      const int pc = ((ks << 2) + g) ^ (r15 & 7);
      bf16x8 af2[4], bfr[4];
      #pragma unroll
      for (int mi = 0; mi < 4; mi++)
        af2[mi] = *(const bf16x8*)&As[((wm << 6) + mi * 16 + r15) * 64 + (pc << 3)];
      #pragma unroll
      for (int ni = 0; ni < 4; ni++)
        bfr[ni] = *(const bf16x8*)&Bs[((wn << 6) + ni * 16 + r15) * 64 + (pc << 3)];
      #pragma unroll
      for (int mi = 0; mi < 4; mi++)
        #pragma unroll
        for (int ni = 0; ni < 4; ni++)
          acc[mi][ni] = MFMA(af2[mi], bfr[ni], acc[mi][ni]);
    }
    __syncthreads();
  }

  float* Pp = P + ((size_t)split << 22);
  #pragma unroll
  for (int mi = 0; mi < 4; mi++) {
    #pragma unroll
    for (int ni = 0; ni < 4; ni++) {
      int col = n0 + (wn << 6) + ni * 16 + r15;
      #pragma unroll
      for (int j = 0; j < 4; j++) {
        int row = m0 + (wm << 6) + mi * 16 + (g << 2) + j;
        Pp[((size_t)row << 12) + col] = acc[mi][ni][j];
      }
    }
  }
}

// ---------- k_reduce: sum 4 K-splits + bias, transpose to out[b,l,n] ----------
__global__ void k_reduce(const float* __restrict__ P, const float* __restrict__ lin_b,
                         float* __restrict__ out) {
  __shared__ float tile[64][65];
  int b = blockIdx.x >> 6, lt = blockIdx.x & 63;
  int tid = threadIdx.x, c = tid & 63, r0 = tid >> 6;
  const float* Pb = P + (((size_t)b * 64) << 12) + (lt << 6);
  #pragma unroll
  for (int i = 0; i < 16; i++) {
    int node = r0 + i * 4;
    size_t off = ((size_t)node << 12) + c;
    float s = Pb[off] + Pb[off + 4194304] + Pb[off + 8388608] + Pb[off + 12582912];
    tile[node][c] = s;
  }
  __syncthreads();
  #pragma unroll
  for (int i = 0; i < 16; i++) {
    int lo = r0 + i * 4;
    out[((size_t)(b * 4096 + lt * 64 + lo)) * 64 + c] = tile[c][lo] + lin_b[lt * 64 + lo];
  }
}

// ---------- launch ----------
extern "C" void kernel_launch(void* const* d_in, const int* in_sizes, int n_in,
                              void* d_out, int out_size, void* d_ws, size_t ws_size,
                              hipStream_t stream) {
  const float* x      = (const float*)d_in[0];
  const float* emb    = (const float*)d_in[1];
  const float* conv_w = (const float*)d_in[2];
  const float* conv_b = (const float*)d_in[3];
  const float* Wq = (const float*)d_in[4],  *bq = (const float*)d_in[5];
  const float* Wk = (const float*)d_in[6],  *bk = (const float*)d_in[7];
  const float* Wv = (const float*)d_in[8],  *bv = (const float*)d_in[9];
  const float* Wo = (const float*)d_in[10], *bo = (const float*)d_in[11];
  const float* ln1g = (const float*)d_in[12], *ln1b = (const float*)d_in[13];
  const float* ln2g = (const float*)d_in[14], *ln2b = (const float*)d_in[15];
  const float* W1 = (const float*)d_in[16], *b1 = (const float*)d_in[17];
  const float* W2 = (const float*)d_in[18], *b2 = (const float*)d_in[19];
  const float* res1 = (const float*)d_in[20], *res2 = (const float*)d_in[21];
  const float* lin_w = (const float*)d_in[22], *lin_b = (const float*)d_in[23];
  float* out = (float*)d_out;

  char* ws = (char*)d_ws;
  float* bias   = (float*)ws;                                        //    16,384 B
  float* hbuf   = (float*)(ws + 16384);                              // 67,108,864 B (layers)
  float* Ppart  = hbuf;                                              // overlay: GEMM partials (after layers)
  u16*   wt     = (u16*)(ws + 16384 + 67108864);                     // 134,217,728 B
  u16*   Abf    = (u16*)(ws + 16384 + 67108864 + 134217728);         // 33,554,432 B
  u16*   WTb    = (u16*)(ws + 16384 + 67108864 + 134217728 + 33554432); // 196,608 B
  u16* WqT = WTb;                 // 8192 elems (2 layers)
  u16* WkT = WTb + 8192;
  u16* WvT = WTb + 16384;
  u16* WoT = WTb + 24576;
  u16* W1T = WTb + 32768;         // 32768 elems
  u16* W2T = WTb + 65536;         // 32768 elems

  k_bias<<<1, 64, 0, stream>>>(emb, bias);
  k_wprep<<<384, 256, 0, stream>>>(Wq, Wk, Wv, Wo, W1, W2, WqT, WkT, WvT, WoT, W1T, W2T);
  k_conv<<<4096, 256, 0, stream>>>(x, conv_w, conv_b, hbuf);
  k_transpose<<<16384, 256, 0, stream>>>(lin_w, wt);
  for (int l = 0; l < 2; l++)
    k_layer2<<<4096, 256, 0, stream>>>(hbuf, emb, bias,
        WqT + l * 4096, WkT + l * 4096, WvT + l * 4096, WoT + l * 4096,
        W1T + l * 16384, W2T + l * 16384,
        bq + l * 64, bk + l * 64, bv + l * 64, bo + l * 64,
        ln1g + l * 64, ln1b + l * 64, ln2g + l * 64, ln2b + l * 64,
        b1 + l * 256, b2 + l * 64, res1 + l, res2 + l,
        (l == 1) ? Abf : (u16*)nullptr);
  k_gemm2<<<1024, 256, 0, stream>>>(Abf, wt, Ppart);
  k_reduce<<<1024, 256, 0, stream>>>(Ppart, lin_b, out);
}